// Round 1
// baseline (2112.501 us; speedup 1.0000x reference)
//
#include <hip/hip_runtime.h>
#include <math.h>

#define S 4096
#define H 1024
#define FF 3072
#define G 100
#define MAXSPAN 30
#define MAXK 819
#define NBAND (S * MAXSPAN)   // 122880 slots, 122445 valid
#define BAND_COUNT 122445.0

// out layout (float32)
#define O_START 0
#define O_END   819
#define O_MASK  1638
#define O_SEQ   2457
#define O_COST  (2457 + S * H)   // 4196761

// ---------------- helpers ----------------

__device__ __forceinline__ float block_reduce_256(float x, volatile float* red) {
  #pragma unroll
  for (int off = 32; off > 0; off >>= 1) x += __shfl_down(x, off, 64);
  int wid = threadIdx.x >> 6;
  int lane = threadIdx.x & 63;
  __syncthreads();                 // protect red[] reuse across calls
  if (lane == 0) red[wid] = x;
  __syncthreads();
  return red[0] + red[1] + red[2] + red[3];
}

__device__ __forceinline__ unsigned f2key(float f) {
  unsigned b = __float_as_uint(f);
  return (b & 0x80000000u) ? ~b : (b | 0x80000000u);
}

// ---------------- GEMM: C = epi(A@B + bias), A MxK, B KxN row-major ----------------
// 128x128 tile, BK=8, 256 threads, 8x8 micro-tile. EPI: 0 = bias, 1 = gelu(bias+)

template <int EPI>
__global__ __launch_bounds__(256) void gemm_kernel(const float* __restrict__ A,
                                                   const float* __restrict__ B,
                                                   const float* __restrict__ bias,
                                                   float* __restrict__ C,
                                                   int M, int N, int K) {
  __shared__ float As[8][128];
  __shared__ float Bs[8][128];
  const int tid = threadIdx.x;
  const int tx = tid & 15, ty = tid >> 4;
  const int bm = blockIdx.y * 128, bn = blockIdx.x * 128;
  const int ar = tid >> 1, ak = (tid & 1) * 4;
  const int br = tid >> 5, bc = (tid & 31) * 4;
  const float* Aptr = A + (size_t)(bm + ar) * K + ak;
  const float* Bptr = B + (size_t)br * N + bn + bc;

  float acc[8][8];
  #pragma unroll
  for (int r = 0; r < 8; r++)
    #pragma unroll
    for (int c = 0; c < 8; c++) acc[r][c] = 0.0f;

  for (int k0 = 0; k0 < K; k0 += 8) {
    float4 av = *(const float4*)(Aptr + k0);
    float4 bv = *(const float4*)(Bptr + (size_t)k0 * N);
    __syncthreads();
    As[ak + 0][ar] = av.x; As[ak + 1][ar] = av.y;
    As[ak + 2][ar] = av.z; As[ak + 3][ar] = av.w;
    *(float4*)&Bs[br][bc] = bv;
    __syncthreads();
    #pragma unroll
    for (int kk = 0; kk < 8; kk++) {
      float a[8], b[8];
      *(float4*)&a[0] = *(const float4*)&As[kk][ty * 8];
      *(float4*)&a[4] = *(const float4*)&As[kk][ty * 8 + 4];
      *(float4*)&b[0] = *(const float4*)&Bs[kk][tx * 8];
      *(float4*)&b[4] = *(const float4*)&Bs[kk][tx * 8 + 4];
      #pragma unroll
      for (int r = 0; r < 8; r++)
        #pragma unroll
        for (int c = 0; c < 8; c++) acc[r][c] += a[r] * b[c];
    }
  }

  #pragma unroll
  for (int r = 0; r < 8; r++) {
    int m = bm + ty * 8 + r;
    float* crow = C + (size_t)m * N + bn + tx * 8;
    float o[8];
    #pragma unroll
    for (int c = 0; c < 8; c++) {
      float vv = acc[r][c] + bias[bn + tx * 8 + c];
      if (EPI == 1) vv = 0.5f * vv * (1.0f + erff(vv * 0.70710678118654752f));
      o[c] = vv;
    }
    *(float4*)crow = *(float4*)&o[0];
    *(float4*)(crow + 4) = *(float4*)&o[4];
  }
}

// ---------------- LayerNorm (in-place) + dot with w → logits ----------------

__global__ __launch_bounds__(256) void ln_dot_kernel(float* __restrict__ Hb,
                                                     const float* __restrict__ g,
                                                     const float* __restrict__ beta,
                                                     const float* __restrict__ w,
                                                     const float* __restrict__ bsc,
                                                     float* __restrict__ logits) {
  __shared__ float red[4];
  const int row = blockIdx.x, tid = threadIdx.x;
  float* h = Hb + (size_t)row * FF;

  float4 v[3];
  float s = 0.0f;
  #pragma unroll
  for (int t = 0; t < 3; t++) {
    v[t] = *(const float4*)(h + tid * 4 + t * 1024);
    s += v[t].x + v[t].y + v[t].z + v[t].w;
  }
  float mu = block_reduce_256(s, red) * (1.0f / (float)FF);

  float s2 = 0.0f;
  #pragma unroll
  for (int t = 0; t < 3; t++) {
    float dx = v[t].x - mu, dy = v[t].y - mu, dz = v[t].z - mu, dw = v[t].w - mu;
    s2 += dx * dx + dy * dy + dz * dz + dw * dw;
  }
  float var = block_reduce_256(s2, red) * (1.0f / (float)FF);
  float rstd = rsqrtf(var + 1e-5f);

  float dot = 0.0f;
  #pragma unroll
  for (int t = 0; t < 3; t++) {
    int idx = tid * 4 + t * 1024;
    float4 gv = *(const float4*)(g + idx);
    float4 bv = *(const float4*)(beta + idx);
    float4 wv = *(const float4*)(w + idx);
    float4 r;
    r.x = (v[t].x - mu) * rstd * gv.x + bv.x;
    r.y = (v[t].y - mu) * rstd * gv.y + bv.y;
    r.z = (v[t].z - mu) * rstd * gv.z + bv.z;
    r.w = (v[t].w - mu) * rstd * gv.w + bv.w;
    *(float4*)(h + idx) = r;
    dot += r.x * wv.x + r.y * wv.y + r.z * wv.z + r.w * wv.w;
  }
  float dt = block_reduce_256(dot, red);
  if (tid == 0) logits[row] = dt + bsc[0];
}

// ---------------- band joint: band[i][d] = clip(temp[i].end[i+d] + sl[i] + el[i+d]) ----------------

__global__ __launch_bounds__(256) void band_joint_kernel(const float* __restrict__ T,
                                                         const float* __restrict__ E,
                                                         const float* __restrict__ sl,
                                                         const float* __restrict__ el,
                                                         float* __restrict__ band) {
  __shared__ float Ts[FF];
  __shared__ float red[4];
  const int i = blockIdx.x, tid = threadIdx.x;
  const float* tr = T + (size_t)i * FF;
  #pragma unroll
  for (int t = 0; t < 3; t++)
    *(float4*)(Ts + tid * 4 + t * 1024) = *(const float4*)(tr + tid * 4 + t * 1024);
  __syncthreads();
  float my_sl = sl[i];
  for (int d = 0; d < MAXSPAN; d++) {
    int j = i + d;                      // block-uniform branch
    if (j < S) {
      const float* er = E + (size_t)j * FF;
      float acc = 0.0f;
      #pragma unroll
      for (int t = 0; t < 3; t++) {
        int k = tid * 4 + t * 1024;
        float4 e4 = *(const float4*)(er + k);
        float4 t4 = *(const float4*)(Ts + k);
        acc += t4.x * e4.x + t4.y * e4.y + t4.z * e4.z + t4.w * e4.w;
      }
      float tot = block_reduce_256(acc, red);
      if (tid == 0) {
        float vv = tot + my_sl + el[j];
        vv = fminf(fmaxf(vv, -10000.0f), 10000.0f);
        band[i * MAXSPAN + d] = vv;
      }
    } else {
      if (tid == 0) band[i * MAXSPAN + d] = -1e30f;
    }
  }
}

// ---------------- gold marking + costs ----------------

__global__ void mark_gold_kernel(const int* __restrict__ gold, char* __restrict__ mark) {
  int t = threadIdx.x;
  if (t < G) {
    int gs = gold[2 * t], ge = gold[2 * t + 1];
    mark[gs * MAXSPAN + (ge - gs)] = 1;
  }
}

__global__ __launch_bounds__(256) void cost_junk_kernel(const float* __restrict__ band,
                                                        const char* __restrict__ mark,
                                                        double* __restrict__ jacc) {
  __shared__ float red[4];
  int e = blockIdx.x * 256 + threadIdx.x;   // grid covers exactly NBAND
  int i = e / MAXSPAN, d = e - i * MAXSPAN;
  float term = 0.0f;
  if (i + d < S && !mark[e]) {
    float x = band[e];
    float p = 1.0f / (1.0f + expf(-x));
    term = fmaxf(logf(1.0f - p), -100.0f);   // log(0) = -inf -> -100
  }
  float ssum = block_reduce_256(term, red);
  if (threadIdx.x == 0) atomicAdd(jacc, (double)ssum);
}

__global__ __launch_bounds__(256) void finalize_kernel(const float* __restrict__ band,
                                                       const int* __restrict__ gold,
                                                       const double* __restrict__ jacc,
                                                       float* __restrict__ outc) {
  __shared__ float red[4];
  int t = threadIdx.x;
  float term = 0.0f;
  if (t < G) {
    int gs = gold[2 * t], ge = gold[2 * t + 1];
    float x = band[gs * MAXSPAN + (ge - gs)];
    float p = 1.0f / (1.0f + expf(-x));
    term = fmaxf(logf(p), -100.0f);
  }
  float sg = block_reduce_256(term, red);
  if (t == 0) {
    double cost = -((double)sg / (double)G) - ((*jacc) / BAND_COUNT);
    *outc = (float)cost;
  }
}

// ---------------- top-k (single block, radix select + bitonic sort) ----------------

__global__ __launch_bounds__(1024) void topk_kernel(const float* __restrict__ band,
                                                    float* __restrict__ out) {
  __shared__ int hist[256];
  __shared__ unsigned sh_prefix;
  __shared__ int sh_remk;
  __shared__ int idxbuf[1024];
  __shared__ int tiebuf[64];
  __shared__ int cnt_gt, cnt_eq;
  __shared__ int sb[1024];
  const int tid = threadIdx.x;

  unsigned prefix = 0;
  int remk = MAXK;
  for (int pass = 0; pass < 4; pass++) {
    int shift = 24 - pass * 8;
    if (tid < 256) hist[tid] = 0;
    __syncthreads();
    for (int e = tid; e < NBAND; e += 1024) {
      unsigned key = f2key(band[e]);
      bool match = (pass == 0) || ((key >> (shift + 8)) == prefix);
      if (match) atomicAdd(&hist[(key >> shift) & 255], 1);
    }
    __syncthreads();
    if (tid == 0) {
      int cum = 0, b = 255;
      for (; b > 0; b--) {
        if (cum + hist[b] >= remk) break;
        cum += hist[b];
      }
      sh_prefix = (prefix << 8) | (unsigned)b;
      sh_remk = remk - cum;
    }
    __syncthreads();
    prefix = sh_prefix;
    remk = sh_remk;
    __syncthreads();
  }
  const unsigned T = prefix;

  if (tid == 0) { cnt_gt = 0; cnt_eq = 0; }
  __syncthreads();
  for (int e = tid; e < NBAND; e += 1024) {
    unsigned key = f2key(band[e]);
    if (key >= T) {
      int i = e / MAXSPAN, d = e - i * MAXSPAN;
      int fi = i * S + i + d;            // flat index in SxS
      if (key > T) {
        int p = atomicAdd(&cnt_gt, 1);
        if (p < 1024) idxbuf[p] = fi;
      } else {
        int p = atomicAdd(&cnt_eq, 1);
        if (p < 64) tiebuf[p] = fi;
      }
    }
  }
  __syncthreads();
  if (tid == 0) {
    int ngt = cnt_gt < 1024 ? cnt_gt : 1024;
    int ne = cnt_eq < 64 ? cnt_eq : 64;
    for (int a2 = 1; a2 < ne; a2++) {     // sort ties ascending (lowest index first)
      int kv = tiebuf[a2];
      int b2 = a2 - 1;
      while (b2 >= 0 && tiebuf[b2] > kv) { tiebuf[b2 + 1] = tiebuf[b2]; b2--; }
      tiebuf[b2 + 1] = kv;
    }
    int take = remk < ne ? remk : ne;
    for (int q = 0; q < take; q++)
      if (ngt + q < 1024) idxbuf[ngt + q] = tiebuf[q];
  }
  __syncthreads();

  sb[tid] = (tid < MAXK) ? idxbuf[tid] : 0x7FFFFFFF;
  __syncthreads();
  for (int ksz = 2; ksz <= 1024; ksz <<= 1) {
    for (int jj = ksz >> 1; jj > 0; jj >>= 1) {
      int ixj = tid ^ jj;
      if (ixj > tid) {
        int a2 = sb[tid], b2 = sb[ixj];
        bool up = ((tid & ksz) == 0);
        if (up ? (a2 > b2) : (a2 < b2)) { sb[tid] = b2; sb[ixj] = a2; }
      }
      __syncthreads();
    }
  }
  if (tid < MAXK) {
    int fi = sb[tid];
    out[O_START + tid] = (float)(fi >> 12);      // / S
    out[O_END + tid]   = (float)(fi & 4095);     // % S
    out[O_MASK + tid]  = 1.0f;
  }
}

// ---------------- launch ----------------

extern "C" void kernel_launch(void* const* d_in, const int* in_sizes, int n_in,
                              void* d_out, int out_size, void* d_ws, size_t ws_size,
                              hipStream_t stream) {
  (void)in_sizes; (void)n_in; (void)out_size;
  const float* seq    = (const float*)d_in[0];
  const int*   gold   = (const int*)d_in[2];
  const float* W_sm   = (const float*)d_in[3];
  const float* b_sm   = (const float*)d_in[4];
  const float* g_sm   = (const float*)d_in[5];
  const float* be_sm  = (const float*)d_in[6];
  const float* W_em   = (const float*)d_in[7];
  const float* b_em   = (const float*)d_in[8];
  const float* g_em   = (const float*)d_in[9];
  const float* be_em  = (const float*)d_in[10];
  const float* w_st   = (const float*)d_in[11];
  const float* b_st   = (const float*)d_in[12];
  const float* w_en   = (const float*)d_in[13];
  const float* b_en   = (const float*)d_in[14];
  const float* W_s2e  = (const float*)d_in[15];
  const float* b_s2e  = (const float*)d_in[16];
  float* out = (float*)d_out;
  char* ws = (char*)d_ws;

  const size_t SZ_REP = (size_t)S * FF * 4;          // 50331648
  float*  bufS = (float*)(ws);                       // h_start -> start_reps (in-place)
  float*  bufE = (float*)(ws + SZ_REP);              // h_end -> end_reps
  float*  bufT = (float*)(ws + 2 * SZ_REP);          // temp
  float*  band = (float*)(ws + 3 * SZ_REP);          // S*30 f32
  char*   mark = (char*) (ws + 3 * SZ_REP + NBAND * 4);
  double* jacc = (double*)(ws + 3 * SZ_REP + NBAND * 4 + NBAND);  // 8-aligned
  float*  slog = (float*)(ws + 3 * SZ_REP + NBAND * 4 + NBAND + 64);
  float*  elog = slog + S;
  (void)ws_size;

  hipMemsetAsync(mark, 0, NBAND, stream);
  hipMemsetAsync(jacc, 0, 8, stream);

  dim3 gg(FF / 128, S / 128);   // (24, 32)
  gemm_kernel<1><<<gg, 256, 0, stream>>>(seq, W_sm, b_sm, bufS, S, FF, H);
  ln_dot_kernel<<<S, 256, 0, stream>>>(bufS, g_sm, be_sm, w_st, b_st, slog);
  gemm_kernel<1><<<gg, 256, 0, stream>>>(seq, W_em, b_em, bufE, S, FF, H);
  ln_dot_kernel<<<S, 256, 0, stream>>>(bufE, g_em, be_em, w_en, b_en, elog);
  gemm_kernel<0><<<gg, 256, 0, stream>>>(bufS, W_s2e, b_s2e, bufT, S, FF, FF);
  band_joint_kernel<<<S, 256, 0, stream>>>(bufT, bufE, slog, elog, band);

  mark_gold_kernel<<<1, 128, 0, stream>>>(gold, mark);
  cost_junk_kernel<<<NBAND / 256, 256, 0, stream>>>(band, mark, jacc);
  topk_kernel<<<1, 1024, 0, stream>>>(band, out);
  finalize_kernel<<<1, 256, 0, stream>>>(band, gold, jacc, out + O_COST);

  hipMemcpyAsync(out + O_SEQ, seq, (size_t)S * H * 4, hipMemcpyDeviceToDevice, stream);
}

// Round 2
// 1213.692 us; speedup vs baseline: 1.7406x; 1.7406x over previous
//
#include <hip/hip_runtime.h>
#include <math.h>

#define S 4096
#define H 1024
#define FF 3072
#define G 100
#define MAXSPAN 30
#define MAXK 819
#define NBAND (S * MAXSPAN)   // 122880 slots, 122445 valid
#define BAND_COUNT 122445.0

// out layout (float32)
#define O_START 0
#define O_END   819
#define O_MASK  1638
#define O_SEQ   2457
#define O_COST  (2457 + S * H)   // 4196761

typedef __bf16 bf16x8 __attribute__((ext_vector_type(8)));
typedef float f32x4 __attribute__((ext_vector_type(4)));

// ---------------- helpers ----------------

__device__ __forceinline__ float block_reduce_256(float x, volatile float* red) {
  #pragma unroll
  for (int off = 32; off > 0; off >>= 1) x += __shfl_down(x, off, 64);
  int wid = threadIdx.x >> 6;
  int lane = threadIdx.x & 63;
  __syncthreads();
  if (lane == 0) red[wid] = x;
  __syncthreads();
  return red[0] + red[1] + red[2] + red[3];
}

__device__ __forceinline__ unsigned f2key(float f) {
  unsigned b = __float_as_uint(f);
  return (b & 0x80000000u) ? ~b : (b | 0x80000000u);
}

__device__ __forceinline__ unsigned short bf16_rne(float x) {
  unsigned u = __float_as_uint(x);
  unsigned r = ((u >> 16) & 1u) + 0x7FFFu;
  return (unsigned short)((u + r) >> 16);
}

__device__ __forceinline__ void split2(float x, unsigned short& h, unsigned short& l) {
  h = bf16_rne(x);
  float hf = __uint_as_float(((unsigned)h) << 16);
  l = bf16_rne(x - hf);
}

__device__ __forceinline__ void gld16(const void* g, void* l) {
  __builtin_amdgcn_global_load_lds(
      (const __attribute__((address_space(1))) unsigned int*)g,
      (__attribute__((address_space(3))) unsigned int*)l, 16, 0, 0);
}

// ---------------- f32 -> (bf16 hi, bf16 lo) elementwise ----------------

__global__ __launch_bounds__(256) void split_kernel(const float* __restrict__ in,
                                                    unsigned short* __restrict__ hi,
                                                    unsigned short* __restrict__ lo,
                                                    int n) {
  int i = (blockIdx.x * 256 + threadIdx.x) * 4;
  if (i >= n) return;
  float4 v = *(const float4*)(in + i);
  unsigned short h0, h1, h2, h3, l0, l1, l2, l3;
  split2(v.x, h0, l0); split2(v.y, h1, l1); split2(v.z, h2, l2); split2(v.w, h3, l3);
  unsigned long long hp = (unsigned long long)h0 | ((unsigned long long)h1 << 16) |
                          ((unsigned long long)h2 << 32) | ((unsigned long long)h3 << 48);
  unsigned long long lp = (unsigned long long)l0 | ((unsigned long long)l1 << 16) |
                          ((unsigned long long)l2 << 32) | ((unsigned long long)l3 << 48);
  *(unsigned long long*)(hi + i) = hp;
  *(unsigned long long*)(lo + i) = lp;
}

// ---------------- f32 KxN -> transposed (bf16 hi, lo) NxK ----------------

__global__ __launch_bounds__(256) void split_transpose_kernel(const float* __restrict__ in,
                                                              unsigned short* __restrict__ hi,
                                                              unsigned short* __restrict__ lo,
                                                              int K, int N) {
  __shared__ float tile[32][33];
  const int tx = threadIdx.x & 31, ty8 = threadIdx.x >> 5;
  const int bx = blockIdx.x, by = blockIdx.y;   // bx over N/32, by over K/32
  #pragma unroll
  for (int r = ty8; r < 32; r += 8)
    tile[r][tx] = in[(size_t)(by * 32 + r) * N + bx * 32 + tx];
  __syncthreads();
  #pragma unroll
  for (int r = ty8; r < 32; r += 8) {
    float v = tile[tx][r];                       // = in[by*32+tx][bx*32+r]
    unsigned short h, l;
    split2(v, h, l);
    size_t o = (size_t)(bx * 32 + r) * K + by * 32 + tx;
    hi[o] = h; lo[o] = l;
  }
}

// ---------------- MFMA GEMM: C = epi(Ahl @ Bhl^T + bias) ----------------
// A: M x K (hi/lo bf16 row-major), Bt: N x K (hi/lo bf16, pre-transposed)
// 128x128 tile, BK=32, 256 threads = 4 waves, wave tile 64x64 = 4x4 of 16x16.
// 3-product split: C = Ah*Bh + Al*Bh + Ah*Bl. EPI: 0 = bias, 1 = gelu(bias+)

template <int EPI>
__global__ __launch_bounds__(256) void gemm_mfma_kernel(const unsigned short* __restrict__ Ahi,
                                                        const unsigned short* __restrict__ Alo,
                                                        const unsigned short* __restrict__ Bhi,
                                                        const unsigned short* __restrict__ Blo,
                                                        const float* __restrict__ bias,
                                                        float* __restrict__ C,
                                                        int M, int N, int K) {
  // LDS: 4 tiles (Ah, Al, Bh, Bl), each laid out [q][row][8 bf16] = 4*128*16B = 8KB
  __shared__ __align__(16) char smem[32768];
  const int tid = threadIdx.x;
  const int lane = tid & 63;
  const int wid = __builtin_amdgcn_readfirstlane(tid >> 6);
  const int wm = wid >> 1, wn = wid & 1;
  const int bm = blockIdx.y * 128, bn = blockIdx.x * 128;

  // staging: wave `wid` handles q = wid, row-halves c = 0,1 of every tile
  const size_t arow = (size_t)(bm + lane) * K;
  const size_t brow = (size_t)(bn + lane) * K;
  const int q8 = wid * 8;                         // k offset within BK for this wave
  const size_t half = (size_t)64 * K;
  const int ldsq = wid * 2048;                    // (wid*128 rows)*16B

  // fragment read offsets
  const int qoff = (lane >> 4) * 2048;            // q*128*16
  const int raby = (wm * 64 + (lane & 15)) * 16;  // A row byte off (+ mt*256)
  const int rbby = (wn * 64 + (lane & 15)) * 16;  // B row byte off (+ nt*256)

  f32x4 acc[4][4];
  #pragma unroll
  for (int a = 0; a < 4; a++)
    #pragma unroll
    for (int b = 0; b < 4; b++) acc[a][b] = (f32x4){0.f, 0.f, 0.f, 0.f};

  for (int k0 = 0; k0 < K; k0 += 32) {
    const unsigned short* gAh = Ahi + arow + k0 + q8;
    const unsigned short* gAl = Alo + arow + k0 + q8;
    const unsigned short* gBh = Bhi + brow + k0 + q8;
    const unsigned short* gBl = Blo + brow + k0 + q8;
    __syncthreads();   // previous iteration's reads done before overwrite
    gld16(gAh,        smem +     0 + ldsq);
    gld16(gAh + half, smem +     0 + ldsq + 1024);
    gld16(gAl,        smem +  8192 + ldsq);
    gld16(gAl + half, smem +  8192 + ldsq + 1024);
    gld16(gBh,        smem + 16384 + ldsq);
    gld16(gBh + half, smem + 16384 + ldsq + 1024);
    gld16(gBl,        smem + 24576 + ldsq);
    gld16(gBl + half, smem + 24576 + ldsq + 1024);
    __syncthreads();   // drains vmcnt -> LDS visible

    bf16x8 ah[4], al[4], bh[4], bl[4];
    #pragma unroll
    for (int mt = 0; mt < 4; mt++) {
      ah[mt] = *(const bf16x8*)(smem +     0 + qoff + raby + mt * 256);
      al[mt] = *(const bf16x8*)(smem +  8192 + qoff + raby + mt * 256);
    }
    #pragma unroll
    for (int nt = 0; nt < 4; nt++) {
      bh[nt] = *(const bf16x8*)(smem + 16384 + qoff + rbby + nt * 256);
      bl[nt] = *(const bf16x8*)(smem + 24576 + qoff + rbby + nt * 256);
    }
    #pragma unroll
    for (int mt = 0; mt < 4; mt++)
      #pragma unroll
      for (int nt = 0; nt < 4; nt++) {
        acc[mt][nt] = __builtin_amdgcn_mfma_f32_16x16x32_bf16(ah[mt], bh[nt], acc[mt][nt], 0, 0, 0);
        acc[mt][nt] = __builtin_amdgcn_mfma_f32_16x16x32_bf16(al[mt], bh[nt], acc[mt][nt], 0, 0, 0);
        acc[mt][nt] = __builtin_amdgcn_mfma_f32_16x16x32_bf16(ah[mt], bl[nt], acc[mt][nt], 0, 0, 0);
      }
  }

  // epilogue: C/D layout col=lane&15, row=(lane>>4)*4+reg
  #pragma unroll
  for (int mt = 0; mt < 4; mt++) {
    #pragma unroll
    for (int nt = 0; nt < 4; nt++) {
      int row0 = bm + wm * 64 + mt * 16 + (lane >> 4) * 4;
      int col  = bn + wn * 64 + nt * 16 + (lane & 15);
      float bb = bias[col];
      #pragma unroll
      for (int r = 0; r < 4; r++) {
        float v = acc[mt][nt][r] + bb;
        if (EPI == 1) v = 0.5f * v * (1.0f + erff(v * 0.70710678118654752f));
        C[(size_t)(row0 + r) * N + col] = v;
      }
    }
  }
}

// ---------------- LayerNorm (in-place) + dot with w -> logits ----------------

__global__ __launch_bounds__(256) void ln_dot_kernel(float* __restrict__ Hb,
                                                     const float* __restrict__ g,
                                                     const float* __restrict__ beta,
                                                     const float* __restrict__ w,
                                                     const float* __restrict__ bsc,
                                                     float* __restrict__ logits) {
  __shared__ float red[4];
  const int row = blockIdx.x, tid = threadIdx.x;
  float* h = Hb + (size_t)row * FF;

  float4 v[3];
  float s = 0.0f;
  #pragma unroll
  for (int t = 0; t < 3; t++) {
    v[t] = *(const float4*)(h + tid * 4 + t * 1024);
    s += v[t].x + v[t].y + v[t].z + v[t].w;
  }
  float mu = block_reduce_256(s, red) * (1.0f / (float)FF);

  float s2 = 0.0f;
  #pragma unroll
  for (int t = 0; t < 3; t++) {
    float dx = v[t].x - mu, dy = v[t].y - mu, dz = v[t].z - mu, dw = v[t].w - mu;
    s2 += dx * dx + dy * dy + dz * dz + dw * dw;
  }
  float var = block_reduce_256(s2, red) * (1.0f / (float)FF);
  float rstd = rsqrtf(var + 1e-5f);

  float dot = 0.0f;
  #pragma unroll
  for (int t = 0; t < 3; t++) {
    int idx = tid * 4 + t * 1024;
    float4 gv = *(const float4*)(g + idx);
    float4 bv = *(const float4*)(beta + idx);
    float4 wv = *(const float4*)(w + idx);
    float4 r;
    r.x = (v[t].x - mu) * rstd * gv.x + bv.x;
    r.y = (v[t].y - mu) * rstd * gv.y + bv.y;
    r.z = (v[t].z - mu) * rstd * gv.z + bv.z;
    r.w = (v[t].w - mu) * rstd * gv.w + bv.w;
    *(float4*)(h + idx) = r;
    dot += r.x * wv.x + r.y * wv.y + r.z * wv.z + r.w * wv.w;
  }
  float dt = block_reduce_256(dot, red);
  if (tid == 0) logits[row] = dt + bsc[0];
}

// ---------------- band joint ----------------

__global__ __launch_bounds__(256) void band_joint_kernel(const float* __restrict__ T,
                                                         const float* __restrict__ E,
                                                         const float* __restrict__ sl,
                                                         const float* __restrict__ el,
                                                         float* __restrict__ band) {
  __shared__ float Ts[FF];
  __shared__ float red[4];
  const int i = blockIdx.x, tid = threadIdx.x;
  const float* tr = T + (size_t)i * FF;
  #pragma unroll
  for (int t = 0; t < 3; t++)
    *(float4*)(Ts + tid * 4 + t * 1024) = *(const float4*)(tr + tid * 4 + t * 1024);
  __syncthreads();
  float my_sl = sl[i];
  for (int d = 0; d < MAXSPAN; d++) {
    int j = i + d;
    if (j < S) {
      const float* er = E + (size_t)j * FF;
      float acc = 0.0f;
      #pragma unroll
      for (int t = 0; t < 3; t++) {
        int k = tid * 4 + t * 1024;
        float4 e4 = *(const float4*)(er + k);
        float4 t4 = *(const float4*)(Ts + k);
        acc += t4.x * e4.x + t4.y * e4.y + t4.z * e4.z + t4.w * e4.w;
      }
      float tot = block_reduce_256(acc, red);
      if (tid == 0) {
        float vv = tot + my_sl + el[j];
        vv = fminf(fmaxf(vv, -10000.0f), 10000.0f);
        band[i * MAXSPAN + d] = vv;
      }
    } else {
      if (tid == 0) band[i * MAXSPAN + d] = -1e30f;
    }
  }
}

// ---------------- gold marking + costs ----------------

__global__ void mark_gold_kernel(const int* __restrict__ gold, char* __restrict__ mark) {
  int t = threadIdx.x;
  if (t < G) {
    int gs = gold[2 * t], ge = gold[2 * t + 1];
    mark[gs * MAXSPAN + (ge - gs)] = 1;
  }
}

__global__ __launch_bounds__(256) void cost_junk_kernel(const float* __restrict__ band,
                                                        const char* __restrict__ mark,
                                                        double* __restrict__ jacc) {
  __shared__ float red[4];
  int e = blockIdx.x * 256 + threadIdx.x;
  int i = e / MAXSPAN, d = e - i * MAXSPAN;
  float term = 0.0f;
  if (i + d < S && !mark[e]) {
    float x = band[e];
    float p = 1.0f / (1.0f + expf(-x));
    term = fmaxf(logf(1.0f - p), -100.0f);
  }
  float ssum = block_reduce_256(term, red);
  if (threadIdx.x == 0) atomicAdd(jacc, (double)ssum);
}

__global__ __launch_bounds__(256) void finalize_kernel(const float* __restrict__ band,
                                                       const int* __restrict__ gold,
                                                       const double* __restrict__ jacc,
                                                       float* __restrict__ outc) {
  __shared__ float red[4];
  int t = threadIdx.x;
  float term = 0.0f;
  if (t < G) {
    int gs = gold[2 * t], ge = gold[2 * t + 1];
    float x = band[gs * MAXSPAN + (ge - gs)];
    float p = 1.0f / (1.0f + expf(-x));
    term = fmaxf(logf(p), -100.0f);
  }
  float sg = block_reduce_256(term, red);
  if (t == 0) {
    double cost = -((double)sg / (double)G) - ((*jacc) / BAND_COUNT);
    *outc = (float)cost;
  }
}

// ---------------- top-k (single block, radix select + bitonic sort) ----------------

__global__ __launch_bounds__(1024) void topk_kernel(const float* __restrict__ band,
                                                    float* __restrict__ out) {
  __shared__ int hist[256];
  __shared__ unsigned sh_prefix;
  __shared__ int sh_remk;
  __shared__ int idxbuf[1024];
  __shared__ int tiebuf[64];
  __shared__ int cnt_gt, cnt_eq;
  __shared__ int sb[1024];
  const int tid = threadIdx.x;

  unsigned prefix = 0;
  int remk = MAXK;
  for (int pass = 0; pass < 4; pass++) {
    int shift = 24 - pass * 8;
    if (tid < 256) hist[tid] = 0;
    __syncthreads();
    for (int e = tid; e < NBAND; e += 1024) {
      unsigned key = f2key(band[e]);
      bool match = (pass == 0) || ((key >> (shift + 8)) == prefix);
      if (match) atomicAdd(&hist[(key >> shift) & 255], 1);
    }
    __syncthreads();
    if (tid == 0) {
      int cum = 0, b = 255;
      for (; b > 0; b--) {
        if (cum + hist[b] >= remk) break;
        cum += hist[b];
      }
      sh_prefix = (prefix << 8) | (unsigned)b;
      sh_remk = remk - cum;
    }
    __syncthreads();
    prefix = sh_prefix;
    remk = sh_remk;
    __syncthreads();
  }
  const unsigned T = prefix;

  if (tid == 0) { cnt_gt = 0; cnt_eq = 0; }
  __syncthreads();
  for (int e = tid; e < NBAND; e += 1024) {
    unsigned key = f2key(band[e]);
    if (key >= T) {
      int i = e / MAXSPAN, d = e - i * MAXSPAN;
      int fi = i * S + i + d;
      if (key > T) {
        int p = atomicAdd(&cnt_gt, 1);
        if (p < 1024) idxbuf[p] = fi;
      } else {
        int p = atomicAdd(&cnt_eq, 1);
        if (p < 64) tiebuf[p] = fi;
      }
    }
  }
  __syncthreads();
  if (tid == 0) {
    int ngt = cnt_gt < 1024 ? cnt_gt : 1024;
    int ne = cnt_eq < 64 ? cnt_eq : 64;
    for (int a2 = 1; a2 < ne; a2++) {
      int kv = tiebuf[a2];
      int b2 = a2 - 1;
      while (b2 >= 0 && tiebuf[b2] > kv) { tiebuf[b2 + 1] = tiebuf[b2]; b2--; }
      tiebuf[b2 + 1] = kv;
    }
    int take = remk < ne ? remk : ne;
    for (int q = 0; q < take; q++)
      if (ngt + q < 1024) idxbuf[ngt + q] = tiebuf[q];
  }
  __syncthreads();

  sb[tid] = (tid < MAXK) ? idxbuf[tid] : 0x7FFFFFFF;
  __syncthreads();
  for (int ksz = 2; ksz <= 1024; ksz <<= 1) {
    for (int jj = ksz >> 1; jj > 0; jj >>= 1) {
      int ixj = tid ^ jj;
      if (ixj > tid) {
        int a2 = sb[tid], b2 = sb[ixj];
        bool up = ((tid & ksz) == 0);
        if (up ? (a2 > b2) : (a2 < b2)) { sb[tid] = b2; sb[ixj] = a2; }
      }
      __syncthreads();
    }
  }
  if (tid < MAXK) {
    int fi = sb[tid];
    out[O_START + tid] = (float)(fi >> 12);
    out[O_END + tid]   = (float)(fi & 4095);
    out[O_MASK + tid]  = 1.0f;
  }
}

// ---------------- launch ----------------

extern "C" void kernel_launch(void* const* d_in, const int* in_sizes, int n_in,
                              void* d_out, int out_size, void* d_ws, size_t ws_size,
                              hipStream_t stream) {
  (void)in_sizes; (void)n_in; (void)out_size; (void)ws_size;
  const float* seq    = (const float*)d_in[0];
  const int*   gold   = (const int*)d_in[2];
  const float* W_sm   = (const float*)d_in[3];
  const float* b_sm   = (const float*)d_in[4];
  const float* g_sm   = (const float*)d_in[5];
  const float* be_sm  = (const float*)d_in[6];
  const float* W_em   = (const float*)d_in[7];
  const float* b_em   = (const float*)d_in[8];
  const float* g_em   = (const float*)d_in[9];
  const float* be_em  = (const float*)d_in[10];
  const float* w_st   = (const float*)d_in[11];
  const float* b_st   = (const float*)d_in[12];
  const float* w_en   = (const float*)d_in[13];
  const float* b_en   = (const float*)d_in[14];
  const float* W_s2e  = (const float*)d_in[15];
  const float* b_s2e  = (const float*)d_in[16];
  float* out = (float*)d_out;
  char* ws = (char*)d_ws;

  const size_t SZ_REP = (size_t)S * FF * 4;          // 50331648
  float*  bufS = (float*)(ws);                       // start_reps f32
  float*  bufE = (float*)(ws + SZ_REP);              // end_reps f32
  float*  bufT = (float*)(ws + 2 * SZ_REP);          // temp f32
  // R3: seq hi/lo (8.4MB each) during GEMM1/2; reused as a3 hi/lo (25.2MB each)
  char* R3 = ws + 3 * SZ_REP;
  unsigned short* seqhi = (unsigned short*)R3;
  unsigned short* seqlo = (unsigned short*)(R3 + (size_t)S * H * 2);
  unsigned short* a3hi  = (unsigned short*)R3;
  unsigned short* a3lo  = (unsigned short*)(R3 + (size_t)S * FF * 2);
  // R4: transposed weight hi/lo (max = W_s2e: 3072*3072*2 = 18.87MB each)
  char* R4 = ws + 4 * SZ_REP;
  unsigned short* wbhi = (unsigned short*)R4;
  unsigned short* wblo = (unsigned short*)(R4 + (size_t)FF * FF * 2);
  // R5: small
  char* R5 = R4 + 2 * (size_t)FF * FF * 2;
  float*  band = (float*)R5;                          // NBAND f32
  char*   mark = R5 + (size_t)NBAND * 4;
  double* jacc = (double*)(R5 + (size_t)NBAND * 4 + NBAND + 32);  // 8-aligned pad
  float*  slog = (float*)(R5 + (size_t)NBAND * 4 + NBAND + 128);
  float*  elog = slog + S;

  hipMemsetAsync(mark, 0, NBAND, stream);
  hipMemsetAsync(jacc, 0, 8, stream);

  dim3 gg(FF / 128, S / 128);   // (24, 32)

  // seq -> hi/lo
  split_kernel<<<(S * H) / 1024, 256, 0, stream>>>(seq, seqhi, seqlo, S * H);
  // W_sm -> transposed hi/lo ; GEMM1 (gelu)
  split_transpose_kernel<<<dim3(FF / 32, H / 32), 256, 0, stream>>>(W_sm, wbhi, wblo, H, FF);
  gemm_mfma_kernel<1><<<gg, 256, 0, stream>>>(seqhi, seqlo, wbhi, wblo, b_sm, bufS, S, FF, H);
  ln_dot_kernel<<<S, 256, 0, stream>>>(bufS, g_sm, be_sm, w_st, b_st, slog);
  // W_em -> transposed hi/lo (reuses R4, stream-ordered after GEMM1) ; GEMM2
  split_transpose_kernel<<<dim3(FF / 32, H / 32), 256, 0, stream>>>(W_em, wbhi, wblo, H, FF);
  gemm_mfma_kernel<1><<<gg, 256, 0, stream>>>(seqhi, seqlo, wbhi, wblo, b_em, bufE, S, FF, H);
  ln_dot_kernel<<<S, 256, 0, stream>>>(bufE, g_em, be_em, w_en, b_en, elog);
  // start_reps -> hi/lo (seq hi/lo dead now) ; W_s2e -> transposed hi/lo ; GEMM3
  split_kernel<<<(S * FF) / 1024, 256, 0, stream>>>(bufS, a3hi, a3lo, S * FF);
  split_transpose_kernel<<<dim3(FF / 32, FF / 32), 256, 0, stream>>>(W_s2e, wbhi, wblo, FF, FF);
  gemm_mfma_kernel<0><<<gg, 256, 0, stream>>>(a3hi, a3lo, wbhi, wblo, b_s2e, bufT, S, FF, FF);

  band_joint_kernel<<<S, 256, 0, stream>>>(bufT, bufE, slog, elog, band);

  mark_gold_kernel<<<1, 128, 0, stream>>>(gold, mark);
  cost_junk_kernel<<<NBAND / 256, 256, 0, stream>>>(band, mark, jacc);
  topk_kernel<<<1, 1024, 0, stream>>>(band, out);
  finalize_kernel<<<1, 256, 0, stream>>>(band, gold, jacc, out + O_COST);

  hipMemcpyAsync(out + O_SEQ, seq, (size_t)S * H * 4, hipMemcpyDeviceToDevice, stream);
}

// Round 3
// 888.119 us; speedup vs baseline: 2.3786x; 1.3666x over previous
//
#include <hip/hip_runtime.h>
#include <math.h>

#define S 4096
#define H 1024
#define FF 3072
#define G 100
#define MAXSPAN 30
#define MAXK 819
#define NBAND (S * MAXSPAN)   // 122880 slots, 122445 valid
#define BAND_COUNT 122445.0

// out layout (float32)
#define O_START 0
#define O_END   819
#define O_MASK  1638
#define O_SEQ   2457
#define O_COST  (2457 + S * H)   // 4196761

typedef __bf16 bf16x8 __attribute__((ext_vector_type(8)));
typedef float f32x4 __attribute__((ext_vector_type(4)));

// ---------------- helpers ----------------

__device__ __forceinline__ float block_reduce_256(float x, volatile float* red) {
  #pragma unroll
  for (int off = 32; off > 0; off >>= 1) x += __shfl_down(x, off, 64);
  int wid = threadIdx.x >> 6;
  int lane = threadIdx.x & 63;
  __syncthreads();
  if (lane == 0) red[wid] = x;
  __syncthreads();
  return red[0] + red[1] + red[2] + red[3];
}

__device__ __forceinline__ unsigned f2key(float f) {
  unsigned b = __float_as_uint(f);
  return (b & 0x80000000u) ? ~b : (b | 0x80000000u);
}

__device__ __forceinline__ unsigned short bf16_rne(float x) {
  unsigned u = __float_as_uint(x);
  unsigned r = ((u >> 16) & 1u) + 0x7FFFu;
  return (unsigned short)((u + r) >> 16);
}

__device__ __forceinline__ void split2(float x, unsigned short& h, unsigned short& l) {
  h = bf16_rne(x);
  float hf = __uint_as_float(((unsigned)h) << 16);
  l = bf16_rne(x - hf);
}

__device__ __forceinline__ void gld16(const void* g, void* l) {
  __builtin_amdgcn_global_load_lds(
      (const __attribute__((address_space(1))) unsigned int*)g,
      (__attribute__((address_space(3))) unsigned int*)l, 16, 0, 0);
}

// ---------------- pack kernels: f32 -> hi/lo bf16, tiled [panel][kq][r][8] ----------------
// tiled element offset = panel*(128*K) + kq*1024 + r*8 + s   (panel = row/128, kq = k/8)

// A-side: source row-major M x K (no transpose). Grid (K/32, M/32), 256 thr.
__global__ __launch_bounds__(256) void pack_a_kernel(const float* __restrict__ A,
                                                     unsigned short* __restrict__ hi,
                                                     unsigned short* __restrict__ lo,
                                                     int K) {
  __shared__ float tile[32][33];
  const int t = threadIdx.x;
  const int tx = t & 31, ty8 = t >> 5;
  const int k0 = blockIdx.x * 32, r0 = blockIdx.y * 32;
  #pragma unroll
  for (int r = ty8; r < 32; r += 8)
    tile[r][tx] = A[(size_t)(r0 + r) * K + k0 + tx];
  __syncthreads();
  if (t < 128) {
    const int kql = t >> 5;           // 0..3
    const int rl = t & 31;
    unsigned short h8[8], l8[8];
    #pragma unroll
    for (int s = 0; s < 8; s++) split2(tile[rl][kql * 8 + s], h8[s], l8[s]);
    const size_t panel = (size_t)(r0 >> 7);
    const int rloc = (r0 & 127) + rl;
    const size_t off = panel * (size_t)(128 * K) + (size_t)(k0 / 8 + kql) * 1024 + (size_t)rloc * 8;
    *(uint4*)(hi + off) = *(const uint4*)h8;
    *(uint4*)(lo + off) = *(const uint4*)l8;
  }
}

// B-side: source W is K x N row-major; pack B^T (N x K) tiled: panel over n.
// Grid (K/32, N/32), 256 thr.
__global__ __launch_bounds__(256) void pack_bt_kernel(const float* __restrict__ W,
                                                      unsigned short* __restrict__ hi,
                                                      unsigned short* __restrict__ lo,
                                                      int K, int N) {
  __shared__ float tile[32][33];   // tile[k_local][n_local]
  const int t = threadIdx.x;
  const int tx = t & 31, ty8 = t >> 5;
  const int k0 = blockIdx.x * 32, n0 = blockIdx.y * 32;
  #pragma unroll
  for (int r = ty8; r < 32; r += 8)
    tile[r][tx] = W[(size_t)(k0 + r) * N + n0 + tx];
  __syncthreads();
  if (t < 128) {
    const int kql = t >> 5;           // 0..3
    const int nl = t & 31;
    unsigned short h8[8], l8[8];
    #pragma unroll
    for (int s = 0; s < 8; s++) split2(tile[kql * 8 + s][nl], h8[s], l8[s]);
    const size_t panel = (size_t)(n0 >> 7);
    const int nloc = (n0 & 127) + nl;
    const size_t off = panel * (size_t)(128 * K) + (size_t)(k0 / 8 + kql) * 1024 + (size_t)nloc * 8;
    *(uint4*)(hi + off) = *(const uint4*)h8;
    *(uint4*)(lo + off) = *(const uint4*)l8;
  }
}

// ---------------- MFMA GEMM: C = epi(Ahl @ Bhl^T + bias), tiled operands ----------------
// 128x128 tile, BK=32, 256 threads = 4 waves, wave tile 64x64 = 4x4 of 16x16.
// 3-product split: C = Ah*Bh + Al*Bh + Ah*Bl. EPI: 0 = bias, 1 = gelu(bias+)

template <int EPI>
__global__ __launch_bounds__(256) void gemm_mfma_kernel(const unsigned short* __restrict__ Ahi,
                                                        const unsigned short* __restrict__ Alo,
                                                        const unsigned short* __restrict__ Bhi,
                                                        const unsigned short* __restrict__ Blo,
                                                        const float* __restrict__ bias,
                                                        float* __restrict__ C,
                                                        int M, int N, int K) {
  // LDS: 4 tiles (Ah, Al, Bh, Bl), each [q][row][8 bf16] = 4*128*16B = 8KB
  __shared__ __align__(16) char smem[32768];
  const int tid = threadIdx.x;
  const int lane = tid & 63;
  const int wid = __builtin_amdgcn_readfirstlane(tid >> 6);
  const int wm = wid >> 1, wn = wid & 1;
  const int bm = blockIdx.y * 128, bn = blockIdx.x * 128;

  // tiled base byte offsets for this block's panels
  const size_t panAb = (size_t)blockIdx.y * (size_t)(128 * K) * 2;
  const size_t panBb = (size_t)blockIdx.x * (size_t)(128 * K) * 2;
  const char* cAh = (const char*)Ahi + panAb;
  const char* cAl = (const char*)Alo + panAb;
  const char* cBh = (const char*)Bhi + panBb;
  const char* cBl = (const char*)Blo + panBb;
  const int lb = lane * 16;
  const int ldsq = wid * 2048;

  // fragment read offsets
  const int qoff = (lane >> 4) * 2048;            // q*128*16
  const int raby = (wm * 64 + (lane & 15)) * 16;  // A row byte off (+ mt*256)
  const int rbby = (wn * 64 + (lane & 15)) * 16;  // B row byte off (+ nt*256)

  f32x4 acc[4][4];
  #pragma unroll
  for (int a = 0; a < 4; a++)
    #pragma unroll
    for (int b = 0; b < 4; b++) acc[a][b] = (f32x4){0.f, 0.f, 0.f, 0.f};

  for (int k0 = 0; k0 < K; k0 += 32) {
    // wave `wid` stages q-block (k0/8 + wid): 2KB contiguous per tile
    const size_t qb = (size_t)((k0 >> 3) + wid) * 2048 + lb;
    __syncthreads();   // previous iteration's reads done before overwrite
    gld16(cAh + qb,        smem +     0 + ldsq);
    gld16(cAh + qb + 1024, smem +     0 + ldsq + 1024);
    gld16(cAl + qb,        smem +  8192 + ldsq);
    gld16(cAl + qb + 1024, smem +  8192 + ldsq + 1024);
    gld16(cBh + qb,        smem + 16384 + ldsq);
    gld16(cBh + qb + 1024, smem + 16384 + ldsq + 1024);
    gld16(cBl + qb,        smem + 24576 + ldsq);
    gld16(cBl + qb + 1024, smem + 24576 + ldsq + 1024);
    __syncthreads();   // drains vmcnt -> LDS visible

    bf16x8 ah[4], al[4], bh[4], bl[4];
    #pragma unroll
    for (int mt = 0; mt < 4; mt++) {
      ah[mt] = *(const bf16x8*)(smem +     0 + qoff + raby + mt * 256);
      al[mt] = *(const bf16x8*)(smem +  8192 + qoff + raby + mt * 256);
    }
    #pragma unroll
    for (int nt = 0; nt < 4; nt++) {
      bh[nt] = *(const bf16x8*)(smem + 16384 + qoff + rbby + nt * 256);
      bl[nt] = *(const bf16x8*)(smem + 24576 + qoff + rbby + nt * 256);
    }
    #pragma unroll
    for (int mt = 0; mt < 4; mt++)
      #pragma unroll
      for (int nt = 0; nt < 4; nt++) {
        acc[mt][nt] = __builtin_amdgcn_mfma_f32_16x16x32_bf16(ah[mt], bh[nt], acc[mt][nt], 0, 0, 0);
        acc[mt][nt] = __builtin_amdgcn_mfma_f32_16x16x32_bf16(al[mt], bh[nt], acc[mt][nt], 0, 0, 0);
        acc[mt][nt] = __builtin_amdgcn_mfma_f32_16x16x32_bf16(ah[mt], bl[nt], acc[mt][nt], 0, 0, 0);
      }
  }

  // epilogue: C/D layout col=lane&15, row=(lane>>4)*4+reg
  #pragma unroll
  for (int mt = 0; mt < 4; mt++) {
    #pragma unroll
    for (int nt = 0; nt < 4; nt++) {
      int row0 = bm + wm * 64 + mt * 16 + (lane >> 4) * 4;
      int col  = bn + wn * 64 + nt * 16 + (lane & 15);
      float bb = bias[col];
      #pragma unroll
      for (int r = 0; r < 4; r++) {
        float v = acc[mt][nt][r] + bb;
        if (EPI == 1) v = 0.5f * v * (1.0f + erff(v * 0.70710678118654752f));
        C[(size_t)(row0 + r) * N + col] = v;
      }
    }
  }
}

// ---------------- LayerNorm (in-place) + dot with w -> logits ----------------

__global__ __launch_bounds__(256) void ln_dot_kernel(float* __restrict__ Hb,
                                                     const float* __restrict__ g,
                                                     const float* __restrict__ beta,
                                                     const float* __restrict__ w,
                                                     const float* __restrict__ bsc,
                                                     float* __restrict__ logits) {
  __shared__ float red[4];
  const int row = blockIdx.x, tid = threadIdx.x;
  float* h = Hb + (size_t)row * FF;

  float4 v[3];
  float s = 0.0f;
  #pragma unroll
  for (int t = 0; t < 3; t++) {
    v[t] = *(const float4*)(h + tid * 4 + t * 1024);
    s += v[t].x + v[t].y + v[t].z + v[t].w;
  }
  float mu = block_reduce_256(s, red) * (1.0f / (float)FF);

  float s2 = 0.0f;
  #pragma unroll
  for (int t = 0; t < 3; t++) {
    float dx = v[t].x - mu, dy = v[t].y - mu, dz = v[t].z - mu, dw = v[t].w - mu;
    s2 += dx * dx + dy * dy + dz * dz + dw * dw;
  }
  float var = block_reduce_256(s2, red) * (1.0f / (float)FF);
  float rstd = rsqrtf(var + 1e-5f);

  float dot = 0.0f;
  #pragma unroll
  for (int t = 0; t < 3; t++) {
    int idx = tid * 4 + t * 1024;
    float4 gv = *(const float4*)(g + idx);
    float4 bv = *(const float4*)(beta + idx);
    float4 wv = *(const float4*)(w + idx);
    float4 r;
    r.x = (v[t].x - mu) * rstd * gv.x + bv.x;
    r.y = (v[t].y - mu) * rstd * gv.y + bv.y;
    r.z = (v[t].z - mu) * rstd * gv.z + bv.z;
    r.w = (v[t].w - mu) * rstd * gv.w + bv.w;
    *(float4*)(h + idx) = r;
    dot += r.x * wv.x + r.y * wv.y + r.z * wv.z + r.w * wv.w;
  }
  float dt = block_reduce_256(dot, red);
  if (tid == 0) logits[row] = dt + bsc[0];
}

// ---------------- band joint (tiled, LDS E-chunk) ----------------
// Block handles 16 T-rows (i0..i0+15); E rows i0..i0+44 chunked in LDS.
// Thread t: r_l = t>>4, c = t&15; k-slice = c*16..c*16+15 per 256-chunk.

__global__ __launch_bounds__(256) void band_joint_kernel(const float* __restrict__ T,
                                                         const float* __restrict__ E,
                                                         const float* __restrict__ sl,
                                                         const float* __restrict__ el,
                                                         float* __restrict__ band) {
  __shared__ float Elds[45][260];   // 260 = 256 + 4 pad (16B-aligned rows)
  const int t = threadIdx.x;
  const int i0 = blockIdx.x * 16;
  const int r_l = t >> 4, c = t & 15;

  float accd[MAXSPAN];
  #pragma unroll
  for (int d = 0; d < MAXSPAN; d++) accd[d] = 0.0f;

  for (int k0 = 0; k0 < FF; k0 += 256) {
    // T slice into registers (16 f32)
    const float* trow = T + (size_t)(i0 + r_l) * FF + k0 + c * 16;
    float4 tv0 = *(const float4*)(trow + 0);
    float4 tv1 = *(const float4*)(trow + 4);
    float4 tv2 = *(const float4*)(trow + 8);
    float4 tv3 = *(const float4*)(trow + 12);
    __syncthreads();   // protect Elds before overwrite
    for (int rr = t >> 6; rr < 45; rr += 4) {
      int gr = i0 + rr;
      int cc = (t & 63) * 4;
      float4 ev = {0.f, 0.f, 0.f, 0.f};
      if (gr < S) ev = *(const float4*)(E + (size_t)gr * FF + k0 + cc);
      *(float4*)&Elds[rr][cc] = ev;
    }
    __syncthreads();
    #pragma unroll
    for (int d = 0; d < MAXSPAN; d++) {
      const float* er = &Elds[r_l + d][c * 16];
      float4 e0 = *(const float4*)(er + 0);
      float4 e1 = *(const float4*)(er + 4);
      float4 e2 = *(const float4*)(er + 8);
      float4 e3 = *(const float4*)(er + 12);
      accd[d] += tv0.x * e0.x + tv0.y * e0.y + tv0.z * e0.z + tv0.w * e0.w
               + tv1.x * e1.x + tv1.y * e1.y + tv1.z * e1.z + tv1.w * e1.w
               + tv2.x * e2.x + tv2.y * e2.y + tv2.z * e2.z + tv2.w * e2.w
               + tv3.x * e3.x + tv3.y * e3.y + tv3.z * e3.z + tv3.w * e3.w;
    }
  }

  const int i = i0 + r_l;
  const float my_sl = sl[i];
  #pragma unroll
  for (int d = 0; d < MAXSPAN; d++) {
    float v = accd[d];
    v += __shfl_down(v, 8, 16);
    v += __shfl_down(v, 4, 16);
    v += __shfl_down(v, 2, 16);
    v += __shfl_down(v, 1, 16);
    if (c == 0) {
      int j = i + d;
      if (j < S) {
        float vv = v + my_sl + el[j];
        vv = fminf(fmaxf(vv, -10000.0f), 10000.0f);
        band[i * MAXSPAN + d] = vv;
      } else {
        band[i * MAXSPAN + d] = -1e30f;
      }
    }
  }
}

// ---------------- gold marking + costs ----------------

__global__ void mark_gold_kernel(const int* __restrict__ gold, char* __restrict__ mark) {
  int t = threadIdx.x;
  if (t < G) {
    int gs = gold[2 * t], ge = gold[2 * t + 1];
    mark[gs * MAXSPAN + (ge - gs)] = 1;
  }
}

__global__ __launch_bounds__(256) void cost_junk_kernel(const float* __restrict__ band,
                                                        const char* __restrict__ mark,
                                                        double* __restrict__ jacc) {
  __shared__ float red[4];
  int e = blockIdx.x * 256 + threadIdx.x;
  int i = e / MAXSPAN, d = e - i * MAXSPAN;
  float term = 0.0f;
  if (i + d < S && !mark[e]) {
    float x = band[e];
    float p = 1.0f / (1.0f + expf(-x));
    term = fmaxf(logf(1.0f - p), -100.0f);
  }
  float ssum = block_reduce_256(term, red);
  if (threadIdx.x == 0) atomicAdd(jacc, (double)ssum);
}

__global__ __launch_bounds__(256) void finalize_kernel(const float* __restrict__ band,
                                                       const int* __restrict__ gold,
                                                       const double* __restrict__ jacc,
                                                       float* __restrict__ outc) {
  __shared__ float red[4];
  int t = threadIdx.x;
  float term = 0.0f;
  if (t < G) {
    int gs = gold[2 * t], ge = gold[2 * t + 1];
    float x = band[gs * MAXSPAN + (ge - gs)];
    float p = 1.0f / (1.0f + expf(-x));
    term = fmaxf(logf(p), -100.0f);
  }
  float sg = block_reduce_256(term, red);
  if (t == 0) {
    double cost = -((double)sg / (double)G) - ((*jacc) / BAND_COUNT);
    *outc = (float)cost;
  }
}

// ---------------- top-k (single block, radix select + bitonic sort) ----------------

__global__ __launch_bounds__(1024) void topk_kernel(const float* __restrict__ band,
                                                    float* __restrict__ out) {
  __shared__ int hist[256];
  __shared__ unsigned sh_prefix;
  __shared__ int sh_remk;
  __shared__ int idxbuf[1024];
  __shared__ int tiebuf[64];
  __shared__ int cnt_gt, cnt_eq;
  __shared__ int sb[1024];
  const int tid = threadIdx.x;

  unsigned prefix = 0;
  int remk = MAXK;
  for (int pass = 0; pass < 4; pass++) {
    int shift = 24 - pass * 8;
    if (tid < 256) hist[tid] = 0;
    __syncthreads();
    for (int e = tid; e < NBAND; e += 1024) {
      unsigned key = f2key(band[e]);
      bool match = (pass == 0) || ((key >> (shift + 8)) == prefix);
      if (match) atomicAdd(&hist[(key >> shift) & 255], 1);
    }
    __syncthreads();
    if (tid == 0) {
      int cum = 0, b = 255;
      for (; b > 0; b--) {
        if (cum + hist[b] >= remk) break;
        cum += hist[b];
      }
      sh_prefix = (prefix << 8) | (unsigned)b;
      sh_remk = remk - cum;
    }
    __syncthreads();
    prefix = sh_prefix;
    remk = sh_remk;
    __syncthreads();
  }
  const unsigned T = prefix;

  if (tid == 0) { cnt_gt = 0; cnt_eq = 0; }
  __syncthreads();
  for (int e = tid; e < NBAND; e += 1024) {
    unsigned key = f2key(band[e]);
    if (key >= T) {
      int i = e / MAXSPAN, d = e - i * MAXSPAN;
      int fi = i * S + i + d;
      if (key > T) {
        int p = atomicAdd(&cnt_gt, 1);
        if (p < 1024) idxbuf[p] = fi;
      } else {
        int p = atomicAdd(&cnt_eq, 1);
        if (p < 64) tiebuf[p] = fi;
      }
    }
  }
  __syncthreads();
  if (tid == 0) {
    int ngt = cnt_gt < 1024 ? cnt_gt : 1024;
    int ne = cnt_eq < 64 ? cnt_eq : 64;
    for (int a2 = 1; a2 < ne; a2++) {
      int kv = tiebuf[a2];
      int b2 = a2 - 1;
      while (b2 >= 0 && tiebuf[b2] > kv) { tiebuf[b2 + 1] = tiebuf[b2]; b2--; }
      tiebuf[b2 + 1] = kv;
    }
    int take = remk < ne ? remk : ne;
    for (int q = 0; q < take; q++)
      if (ngt + q < 1024) idxbuf[ngt + q] = tiebuf[q];
  }
  __syncthreads();

  sb[tid] = (tid < MAXK) ? idxbuf[tid] : 0x7FFFFFFF;
  __syncthreads();
  for (int ksz = 2; ksz <= 1024; ksz <<= 1) {
    for (int jj = ksz >> 1; jj > 0; jj >>= 1) {
      int ixj = tid ^ jj;
      if (ixj > tid) {
        int a2 = sb[tid], b2 = sb[ixj];
        bool up = ((tid & ksz) == 0);
        if (up ? (a2 > b2) : (a2 < b2)) { sb[tid] = b2; sb[ixj] = a2; }
      }
      __syncthreads();
    }
  }
  if (tid < MAXK) {
    int fi = sb[tid];
    out[O_START + tid] = (float)(fi >> 12);
    out[O_END + tid]   = (float)(fi & 4095);
    out[O_MASK + tid]  = 1.0f;
  }
}

// ---------------- launch ----------------

extern "C" void kernel_launch(void* const* d_in, const int* in_sizes, int n_in,
                              void* d_out, int out_size, void* d_ws, size_t ws_size,
                              hipStream_t stream) {
  (void)in_sizes; (void)n_in; (void)out_size; (void)ws_size;
  const float* seq    = (const float*)d_in[0];
  const int*   gold   = (const int*)d_in[2];
  const float* W_sm   = (const float*)d_in[3];
  const float* b_sm   = (const float*)d_in[4];
  const float* g_sm   = (const float*)d_in[5];
  const float* be_sm  = (const float*)d_in[6];
  const float* W_em   = (const float*)d_in[7];
  const float* b_em   = (const float*)d_in[8];
  const float* g_em   = (const float*)d_in[9];
  const float* be_em  = (const float*)d_in[10];
  const float* w_st   = (const float*)d_in[11];
  const float* b_st   = (const float*)d_in[12];
  const float* w_en   = (const float*)d_in[13];
  const float* b_en   = (const float*)d_in[14];
  const float* W_s2e  = (const float*)d_in[15];
  const float* b_s2e  = (const float*)d_in[16];
  float* out = (float*)d_out;
  char* ws = (char*)d_ws;

  const size_t SZ_REP = (size_t)S * FF * 4;          // 50331648
  float*  bufS = (float*)(ws);                       // start_reps f32
  float*  bufE = (float*)(ws + SZ_REP);              // end_reps f32
  float*  bufT = (float*)(ws + 2 * SZ_REP);          // temp f32
  // R3: seq hi/lo tiled (8.4MB each) during GEMM1/2; reused as a3 hi/lo tiled
  char* R3 = ws + 3 * SZ_REP;
  unsigned short* seqhi = (unsigned short*)R3;
  unsigned short* seqlo = (unsigned short*)(R3 + (size_t)S * H * 2);
  unsigned short* a3hi  = (unsigned short*)R3;
  unsigned short* a3lo  = (unsigned short*)(R3 + (size_t)S * FF * 2);
  // R4: tiled weight hi/lo (max = W_s2e: 3072*3072*2 = 18.87MB each)
  char* R4 = ws + 4 * SZ_REP;
  unsigned short* wbhi = (unsigned short*)R4;
  unsigned short* wblo = (unsigned short*)(R4 + (size_t)FF * FF * 2);
  // R5: small
  char* R5 = R4 + 2 * (size_t)FF * FF * 2;
  float*  band = (float*)R5;                          // NBAND f32
  char*   mark = R5 + (size_t)NBAND * 4;
  double* jacc = (double*)(R5 + (size_t)NBAND * 4 + NBAND + 32);
  float*  slog = (float*)(R5 + (size_t)NBAND * 4 + NBAND + 128);
  float*  elog = slog + S;

  hipMemsetAsync(mark, 0, NBAND, stream);
  hipMemsetAsync(jacc, 0, 8, stream);

  dim3 gg(FF / 128, S / 128);   // (24, 32)

  // seq -> tiled hi/lo (M=S, K=H)
  pack_a_kernel<<<dim3(H / 32, S / 32), 256, 0, stream>>>(seq, seqhi, seqlo, H);
  // W_sm -> tiled B^T hi/lo ; GEMM1 (gelu)
  pack_bt_kernel<<<dim3(H / 32, FF / 32), 256, 0, stream>>>(W_sm, wbhi, wblo, H, FF);
  gemm_mfma_kernel<1><<<gg, 256, 0, stream>>>(seqhi, seqlo, wbhi, wblo, b_sm, bufS, S, FF, H);
  ln_dot_kernel<<<S, 256, 0, stream>>>(bufS, g_sm, be_sm, w_st, b_st, slog);
  // W_em -> tiled (reuses R4, stream-ordered after GEMM1) ; GEMM2
  pack_bt_kernel<<<dim3(H / 32, FF / 32), 256, 0, stream>>>(W_em, wbhi, wblo, H, FF);
  gemm_mfma_kernel<1><<<gg, 256, 0, stream>>>(seqhi, seqlo, wbhi, wblo, b_em, bufE, S, FF, H);
  ln_dot_kernel<<<S, 256, 0, stream>>>(bufE, g_em, be_em, w_en, b_en, elog);
  // start_reps -> tiled hi/lo (seq tiled dead now) ; W_s2e -> tiled ; GEMM3
  pack_a_kernel<<<dim3(FF / 32, S / 32), 256, 0, stream>>>(bufS, a3hi, a3lo, FF);
  pack_bt_kernel<<<dim3(FF / 32, FF / 32), 256, 0, stream>>>(W_s2e, wbhi, wblo, FF, FF);
  gemm_mfma_kernel<0><<<gg, 256, 0, stream>>>(a3hi, a3lo, wbhi, wblo, b_s2e, bufT, S, FF, FF);

  band_joint_kernel<<<S / 16, 256, 0, stream>>>(bufT, bufE, slog, elog, band);

  mark_gold_kernel<<<1, 128, 0, stream>>>(gold, mark);
  cost_junk_kernel<<<NBAND / 256, 256, 0, stream>>>(band, mark, jacc);
  topk_kernel<<<1, 1024, 0, stream>>>(band, out);
  finalize_kernel<<<1, 256, 0, stream>>>(band, gold, jacc, out + O_COST);

  hipMemcpyAsync(out + O_SEQ, seq, (size_t)S * H * 4, hipMemcpyDeviceToDevice, stream);
}

// Round 4
// 839.392 us; speedup vs baseline: 2.5167x; 1.0581x over previous
//
#include <hip/hip_runtime.h>
#include <math.h>

#define S 4096
#define H 1024
#define FF 3072
#define G 100
#define MAXSPAN 30
#define MAXK 819
#define NBAND (S * MAXSPAN)   // 122880 slots, 122445 valid
#define BAND_COUNT 122445.0

// out layout (float32)
#define O_START 0
#define O_END   819
#define O_MASK  1638
#define O_SEQ   2457
#define O_COST  (2457 + S * H)   // 4196761

typedef __bf16 bf16x8 __attribute__((ext_vector_type(8)));
typedef float f32x4 __attribute__((ext_vector_type(4)));
typedef float f32x16 __attribute__((ext_vector_type(16)));

// ---------------- helpers ----------------

__device__ __forceinline__ float block_reduce_256(float x, volatile float* red) {
  #pragma unroll
  for (int off = 32; off > 0; off >>= 1) x += __shfl_down(x, off, 64);
  int wid = threadIdx.x >> 6;
  int lane = threadIdx.x & 63;
  __syncthreads();
  if (lane == 0) red[wid] = x;
  __syncthreads();
  return red[0] + red[1] + red[2] + red[3];
}

__device__ __forceinline__ unsigned f2key(float f) {
  unsigned b = __float_as_uint(f);
  return (b & 0x80000000u) ? ~b : (b | 0x80000000u);
}

__device__ __forceinline__ unsigned short bf16_rne(float x) {
  unsigned u = __float_as_uint(x);
  unsigned r = ((u >> 16) & 1u) + 0x7FFFu;
  return (unsigned short)((u + r) >> 16);
}

__device__ __forceinline__ void split2(float x, unsigned short& h, unsigned short& l) {
  h = bf16_rne(x);
  float hf = __uint_as_float(((unsigned)h) << 16);
  l = bf16_rne(x - hf);
}

__device__ __forceinline__ void gld16(const void* g, void* l) {
  __builtin_amdgcn_global_load_lds(
      (const __attribute__((address_space(1))) unsigned int*)g,
      (__attribute__((address_space(3))) unsigned int*)l, 16, 0, 0);
}

// ---------------- pack kernels: f32 -> hi/lo bf16, tiled [panel][kq][r][8] ----------------
// tiled element offset = panel*(128*K) + kq*1024 + r*8 + s   (panel = row/128, kq = k/8)

// A-side: source row-major M x K (no transpose). Grid (K/32, M/32), 256 thr.
__global__ __launch_bounds__(256) void pack_a_kernel(const float* __restrict__ A,
                                                     unsigned short* __restrict__ hi,
                                                     unsigned short* __restrict__ lo,
                                                     int K) {
  __shared__ float tile[32][33];
  const int t = threadIdx.x;
  const int tx = t & 31, ty8 = t >> 5;
  const int k0 = blockIdx.x * 32, r0 = blockIdx.y * 32;
  #pragma unroll
  for (int r = ty8; r < 32; r += 8)
    tile[r][tx] = A[(size_t)(r0 + r) * K + k0 + tx];
  __syncthreads();
  if (t < 128) {
    const int kql = t >> 5;           // 0..3
    const int rl = t & 31;
    unsigned short h8[8], l8[8];
    #pragma unroll
    for (int s = 0; s < 8; s++) split2(tile[rl][kql * 8 + s], h8[s], l8[s]);
    const size_t panel = (size_t)(r0 >> 7);
    const int rloc = (r0 & 127) + rl;
    const size_t off = panel * (size_t)(128 * K) + (size_t)(k0 / 8 + kql) * 1024 + (size_t)rloc * 8;
    *(uint4*)(hi + off) = *(const uint4*)h8;
    *(uint4*)(lo + off) = *(const uint4*)l8;
  }
}

// A-side with fused LayerNorm: val = (A - mu[row]) * rstd[row] * g[k] + beta[k]
__global__ __launch_bounds__(256) void pack_ln_a_kernel(const float* __restrict__ A,
                                                        const float* __restrict__ mu,
                                                        const float* __restrict__ rstd,
                                                        const float* __restrict__ g,
                                                        const float* __restrict__ beta,
                                                        unsigned short* __restrict__ hi,
                                                        unsigned short* __restrict__ lo,
                                                        int K) {
  __shared__ float tile[32][33];
  const int t = threadIdx.x;
  const int tx = t & 31, ty8 = t >> 5;
  const int k0 = blockIdx.x * 32, r0 = blockIdx.y * 32;
  #pragma unroll
  for (int r = ty8; r < 32; r += 8)
    tile[r][tx] = A[(size_t)(r0 + r) * K + k0 + tx];
  __syncthreads();
  if (t < 128) {
    const int kql = t >> 5;           // 0..3
    const int rl = t & 31;
    const int row = r0 + rl;
    const float m = mu[row], rs = rstd[row];
    float4 g0 = *(const float4*)(g + k0 + kql * 8);
    float4 g1 = *(const float4*)(g + k0 + kql * 8 + 4);
    float4 b0 = *(const float4*)(beta + k0 + kql * 8);
    float4 b1 = *(const float4*)(beta + k0 + kql * 8 + 4);
    float gv[8] = {g0.x, g0.y, g0.z, g0.w, g1.x, g1.y, g1.z, g1.w};
    float bv[8] = {b0.x, b0.y, b0.z, b0.w, b1.x, b1.y, b1.z, b1.w};
    unsigned short h8[8], l8[8];
    #pragma unroll
    for (int s = 0; s < 8; s++) {
      float v = (tile[rl][kql * 8 + s] - m) * rs * gv[s] + bv[s];
      split2(v, h8[s], l8[s]);
    }
    const size_t panel = (size_t)(r0 >> 7);
    const int rloc = (r0 & 127) + rl;
    const size_t off = panel * (size_t)(128 * K) + (size_t)(k0 / 8 + kql) * 1024 + (size_t)rloc * 8;
    *(uint4*)(hi + off) = *(const uint4*)h8;
    *(uint4*)(lo + off) = *(const uint4*)l8;
  }
}

// B-side: source W is K x N row-major; pack B^T (N x K) tiled: panel over n.
// Grid (K/32, N/32), 256 thr.
__global__ __launch_bounds__(256) void pack_bt_kernel(const float* __restrict__ W,
                                                      unsigned short* __restrict__ hi,
                                                      unsigned short* __restrict__ lo,
                                                      int K, int N) {
  __shared__ float tile[32][33];   // tile[k_local][n_local]
  const int t = threadIdx.x;
  const int tx = t & 31, ty8 = t >> 5;
  const int k0 = blockIdx.x * 32, n0 = blockIdx.y * 32;
  #pragma unroll
  for (int r = ty8; r < 32; r += 8)
    tile[r][tx] = W[(size_t)(k0 + r) * N + n0 + tx];
  __syncthreads();
  if (t < 128) {
    const int kql = t >> 5;           // 0..3
    const int nl = t & 31;
    unsigned short h8[8], l8[8];
    #pragma unroll
    for (int s = 0; s < 8; s++) split2(tile[kql * 8 + s][nl], h8[s], l8[s]);
    const size_t panel = (size_t)(n0 >> 7);
    const int nloc = (n0 & 127) + nl;
    const size_t off = panel * (size_t)(128 * K) + (size_t)(k0 / 8 + kql) * 1024 + (size_t)nloc * 8;
    *(uint4*)(hi + off) = *(const uint4*)h8;
    *(uint4*)(lo + off) = *(const uint4*)l8;
  }
}

// ---------------- MFMA GEMM: C = epi(Ahl @ Bhl^T + bias), tiled operands ----------------
// 128x128 tile, BK=32, 256 threads = 4 waves, wave tile 64x64 = 2x2 of 32x32.
// v_mfma_f32_32x32x16_bf16: A frag 8 bf16 (m=lane&31, k=(lane>>5)*8+j),
// C/D: col=lane&31, row=(reg&3)+8*(reg>>2)+4*(lane>>5)  [m74/m101 verified]
// 3-product split: C = Ah*Bh + Al*Bh + Ah*Bl. EPI: 0 = bias, 1 = gelu(bias+)

template <int EPI>
__global__ __launch_bounds__(256) void gemm_mfma_kernel(const unsigned short* __restrict__ Ahi,
                                                        const unsigned short* __restrict__ Alo,
                                                        const unsigned short* __restrict__ Bhi,
                                                        const unsigned short* __restrict__ Blo,
                                                        const float* __restrict__ bias,
                                                        float* __restrict__ C,
                                                        int M, int N, int K) {
  // LDS: 4 tiles (Ah, Al, Bh, Bl), each [q][row][8 bf16] = 4*128*16B = 8KB
  __shared__ __align__(16) char smem[32768];
  const int tid = threadIdx.x;
  const int lane = tid & 63;
  const int wid = __builtin_amdgcn_readfirstlane(tid >> 6);
  const int wm = wid >> 1, wn = wid & 1;
  const int bm = blockIdx.y * 128, bn = blockIdx.x * 128;

  // tiled base byte offsets for this block's panels
  const size_t panAb = (size_t)blockIdx.y * (size_t)(128 * K) * 2;
  const size_t panBb = (size_t)blockIdx.x * (size_t)(128 * K) * 2;
  const char* cAh = (const char*)Ahi + panAb;
  const char* cAl = (const char*)Alo + panAb;
  const char* cBh = (const char*)Bhi + panBb;
  const char* cBl = (const char*)Blo + panBb;
  const int lb = lane * 16;
  const int ldsq = wid * 2048;

  // fragment read offsets (32x32x16): q = kstep*2 + khalf
  const int khalf = lane >> 5;
  const int r31 = lane & 31;
  const int abase = khalf * 2048 + (wm * 64 + r31) * 16;  // + ks*4096 + mt*512
  const int bbase = khalf * 2048 + (wn * 64 + r31) * 16;  // + ks*4096 + nt*512

  f32x16 acc[2][2];
  #pragma unroll
  for (int a = 0; a < 2; a++)
    #pragma unroll
    for (int b = 0; b < 2; b++)
      #pragma unroll
      for (int r = 0; r < 16; r++) acc[a][b][r] = 0.0f;

  for (int k0 = 0; k0 < K; k0 += 32) {
    // wave `wid` stages q-block (k0/8 + wid): 2KB contiguous per tile
    const size_t qb = (size_t)((k0 >> 3) + wid) * 2048 + lb;
    __syncthreads();   // previous iteration's reads done before overwrite
    gld16(cAh + qb,        smem +     0 + ldsq);
    gld16(cAh + qb + 1024, smem +     0 + ldsq + 1024);
    gld16(cAl + qb,        smem +  8192 + ldsq);
    gld16(cAl + qb + 1024, smem +  8192 + ldsq + 1024);
    gld16(cBh + qb,        smem + 16384 + ldsq);
    gld16(cBh + qb + 1024, smem + 16384 + ldsq + 1024);
    gld16(cBl + qb,        smem + 24576 + ldsq);
    gld16(cBl + qb + 1024, smem + 24576 + ldsq + 1024);
    __syncthreads();   // drains vmcnt -> LDS visible

    bf16x8 ah[2][2], al[2][2], bh[2][2], bl[2][2];   // [kstep][tile]
    #pragma unroll
    for (int ks = 0; ks < 2; ks++) {
      #pragma unroll
      for (int mt = 0; mt < 2; mt++) {
        ah[ks][mt] = *(const bf16x8*)(smem +     0 + ks * 4096 + abase + mt * 512);
        al[ks][mt] = *(const bf16x8*)(smem +  8192 + ks * 4096 + abase + mt * 512);
      }
      #pragma unroll
      for (int nt = 0; nt < 2; nt++) {
        bh[ks][nt] = *(const bf16x8*)(smem + 16384 + ks * 4096 + bbase + nt * 512);
        bl[ks][nt] = *(const bf16x8*)(smem + 24576 + ks * 4096 + bbase + nt * 512);
      }
    }
    #pragma unroll
    for (int ks = 0; ks < 2; ks++)
      #pragma unroll
      for (int mt = 0; mt < 2; mt++)
        #pragma unroll
        for (int nt = 0; nt < 2; nt++) {
          acc[mt][nt] = __builtin_amdgcn_mfma_f32_32x32x16_bf16(ah[ks][mt], bh[ks][nt], acc[mt][nt], 0, 0, 0);
          acc[mt][nt] = __builtin_amdgcn_mfma_f32_32x32x16_bf16(al[ks][mt], bh[ks][nt], acc[mt][nt], 0, 0, 0);
          acc[mt][nt] = __builtin_amdgcn_mfma_f32_32x32x16_bf16(ah[ks][mt], bl[ks][nt], acc[mt][nt], 0, 0, 0);
        }
  }

  // epilogue: col=lane&31, row=(reg&3)+8*(reg>>2)+4*khalf
  #pragma unroll
  for (int mt = 0; mt < 2; mt++) {
    #pragma unroll
    for (int nt = 0; nt < 2; nt++) {
      const int colg = bn + wn * 64 + nt * 32 + r31;
      const float bb = bias[colg];
      #pragma unroll
      for (int reg = 0; reg < 16; reg++) {
        const int rowl = (reg & 3) + 8 * (reg >> 2) + 4 * khalf;
        const int rowg = bm + wm * 64 + mt * 32 + rowl;
        float v = acc[mt][nt][reg] + bb;
        if (EPI == 1) v = 0.5f * v * (1.0f + erff(v * 0.70710678118654752f));
        C[(size_t)rowg * N + colg] = v;
      }
    }
  }
}

// ---------------- LayerNorm + dot with w -> logits ----------------
// WRITEBACK=1: write normalized rows in place. WRITEBACK=0: stats-only (mu/rstd out).

template <int WRITEBACK>
__global__ __launch_bounds__(256) void ln_dot_kernel(float* __restrict__ Hb,
                                                     const float* __restrict__ g,
                                                     const float* __restrict__ beta,
                                                     const float* __restrict__ w,
                                                     const float* __restrict__ bsc,
                                                     float* __restrict__ logits,
                                                     float* __restrict__ mu_out,
                                                     float* __restrict__ rstd_out) {
  __shared__ float red[4];
  const int row = blockIdx.x, tid = threadIdx.x;
  float* h = Hb + (size_t)row * FF;

  float4 v[3];
  float s = 0.0f;
  #pragma unroll
  for (int t = 0; t < 3; t++) {
    v[t] = *(const float4*)(h + tid * 4 + t * 1024);
    s += v[t].x + v[t].y + v[t].z + v[t].w;
  }
  float mu = block_reduce_256(s, red) * (1.0f / (float)FF);

  float s2 = 0.0f;
  #pragma unroll
  for (int t = 0; t < 3; t++) {
    float dx = v[t].x - mu, dy = v[t].y - mu, dz = v[t].z - mu, dw = v[t].w - mu;
    s2 += dx * dx + dy * dy + dz * dz + dw * dw;
  }
  float var = block_reduce_256(s2, red) * (1.0f / (float)FF);
  float rstd = rsqrtf(var + 1e-5f);

  float dot = 0.0f;
  #pragma unroll
  for (int t = 0; t < 3; t++) {
    int idx = tid * 4 + t * 1024;
    float4 gv = *(const float4*)(g + idx);
    float4 bv = *(const float4*)(beta + idx);
    float4 wv = *(const float4*)(w + idx);
    float4 r;
    r.x = (v[t].x - mu) * rstd * gv.x + bv.x;
    r.y = (v[t].y - mu) * rstd * gv.y + bv.y;
    r.z = (v[t].z - mu) * rstd * gv.z + bv.z;
    r.w = (v[t].w - mu) * rstd * gv.w + bv.w;
    if (WRITEBACK) *(float4*)(h + idx) = r;
    dot += r.x * wv.x + r.y * wv.y + r.z * wv.z + r.w * wv.w;
  }
  float dt = block_reduce_256(dot, red);
  if (tid == 0) {
    logits[row] = dt + bsc[0];
    if (!WRITEBACK) { mu_out[row] = mu; rstd_out[row] = rstd; }
  }
}

// ---------------- band joint (tiled, LDS E-chunk) ----------------

__global__ __launch_bounds__(256) void band_joint_kernel(const float* __restrict__ T,
                                                         const float* __restrict__ E,
                                                         const float* __restrict__ sl,
                                                         const float* __restrict__ el,
                                                         float* __restrict__ band) {
  __shared__ float Elds[45][260];   // 260 = 256 + 4 pad
  const int t = threadIdx.x;
  const int i0 = blockIdx.x * 16;
  const int r_l = t >> 4, c = t & 15;

  float accd[MAXSPAN];
  #pragma unroll
  for (int d = 0; d < MAXSPAN; d++) accd[d] = 0.0f;

  for (int k0 = 0; k0 < FF; k0 += 256) {
    const float* trow = T + (size_t)(i0 + r_l) * FF + k0 + c * 16;
    float4 tv0 = *(const float4*)(trow + 0);
    float4 tv1 = *(const float4*)(trow + 4);
    float4 tv2 = *(const float4*)(trow + 8);
    float4 tv3 = *(const float4*)(trow + 12);
    __syncthreads();
    for (int rr = t >> 6; rr < 45; rr += 4) {
      int gr = i0 + rr;
      int cc = (t & 63) * 4;
      float4 ev = {0.f, 0.f, 0.f, 0.f};
      if (gr < S) ev = *(const float4*)(E + (size_t)gr * FF + k0 + cc);
      *(float4*)&Elds[rr][cc] = ev;
    }
    __syncthreads();
    #pragma unroll
    for (int d = 0; d < MAXSPAN; d++) {
      const float* er = &Elds[r_l + d][c * 16];
      float4 e0 = *(const float4*)(er + 0);
      float4 e1 = *(const float4*)(er + 4);
      float4 e2 = *(const float4*)(er + 8);
      float4 e3 = *(const float4*)(er + 12);
      accd[d] += tv0.x * e0.x + tv0.y * e0.y + tv0.z * e0.z + tv0.w * e0.w
               + tv1.x * e1.x + tv1.y * e1.y + tv1.z * e1.z + tv1.w * e1.w
               + tv2.x * e2.x + tv2.y * e2.y + tv2.z * e2.z + tv2.w * e2.w
               + tv3.x * e3.x + tv3.y * e3.y + tv3.z * e3.z + tv3.w * e3.w;
    }
  }

  const int i = i0 + r_l;
  const float my_sl = sl[i];
  #pragma unroll
  for (int d = 0; d < MAXSPAN; d++) {
    float v = accd[d];
    v += __shfl_down(v, 8, 16);
    v += __shfl_down(v, 4, 16);
    v += __shfl_down(v, 2, 16);
    v += __shfl_down(v, 1, 16);
    if (c == 0) {
      int j = i + d;
      if (j < S) {
        float vv = v + my_sl + el[j];
        vv = fminf(fmaxf(vv, -10000.0f), 10000.0f);
        band[i * MAXSPAN + d] = vv;
      } else {
        band[i * MAXSPAN + d] = -1e30f;
      }
    }
  }
}

// ---------------- gold marking + costs ----------------

__global__ void mark_gold_kernel(const int* __restrict__ gold, char* __restrict__ mark) {
  int t = threadIdx.x;
  if (t < G) {
    int gs = gold[2 * t], ge = gold[2 * t + 1];
    mark[gs * MAXSPAN + (ge - gs)] = 1;
  }
}

__global__ __launch_bounds__(256) void cost_junk_kernel(const float* __restrict__ band,
                                                        const char* __restrict__ mark,
                                                        double* __restrict__ jacc) {
  __shared__ float red[4];
  int e = blockIdx.x * 256 + threadIdx.x;
  int i = e / MAXSPAN, d = e - i * MAXSPAN;
  float term = 0.0f;
  if (i + d < S && !mark[e]) {
    float x = band[e];
    float p = 1.0f / (1.0f + expf(-x));
    term = fmaxf(logf(1.0f - p), -100.0f);
  }
  float ssum = block_reduce_256(term, red);
  if (threadIdx.x == 0) atomicAdd(jacc, (double)ssum);
}

__global__ __launch_bounds__(256) void finalize_kernel(const float* __restrict__ band,
                                                       const int* __restrict__ gold,
                                                       const double* __restrict__ jacc,
                                                       float* __restrict__ outc) {
  __shared__ float red[4];
  int t = threadIdx.x;
  float term = 0.0f;
  if (t < G) {
    int gs = gold[2 * t], ge = gold[2 * t + 1];
    float x = band[gs * MAXSPAN + (ge - gs)];
    float p = 1.0f / (1.0f + expf(-x));
    term = fmaxf(logf(p), -100.0f);
  }
  float sg = block_reduce_256(term, red);
  if (t == 0) {
    double cost = -((double)sg / (double)G) - ((*jacc) / BAND_COUNT);
    *outc = (float)cost;
  }
}

// ---------------- top-k (single block, radix select + bitonic sort) ----------------

__global__ __launch_bounds__(1024) void topk_kernel(const float* __restrict__ band,
                                                    float* __restrict__ out) {
  __shared__ int hist[256];
  __shared__ unsigned sh_prefix;
  __shared__ int sh_remk;
  __shared__ int idxbuf[1024];
  __shared__ int tiebuf[64];
  __shared__ int cnt_gt, cnt_eq;
  __shared__ int sb[1024];
  const int tid = threadIdx.x;

  unsigned prefix = 0;
  int remk = MAXK;
  for (int pass = 0; pass < 4; pass++) {
    int shift = 24 - pass * 8;
    if (tid < 256) hist[tid] = 0;
    __syncthreads();
    for (int e = tid; e < NBAND; e += 1024) {
      unsigned key = f2key(band[e]);
      bool match = (pass == 0) || ((key >> (shift + 8)) == prefix);
      if (match) atomicAdd(&hist[(key >> shift) & 255], 1);
    }
    __syncthreads();
    if (tid == 0) {
      int cum = 0, b = 255;
      for (; b > 0; b--) {
        if (cum + hist[b] >= remk) break;
        cum += hist[b];
      }
      sh_prefix = (prefix << 8) | (unsigned)b;
      sh_remk = remk - cum;
    }
    __syncthreads();
    prefix = sh_prefix;
    remk = sh_remk;
    __syncthreads();
  }
  const unsigned T = prefix;

  if (tid == 0) { cnt_gt = 0; cnt_eq = 0; }
  __syncthreads();
  for (int e = tid; e < NBAND; e += 1024) {
    unsigned key = f2key(band[e]);
    if (key >= T) {
      int i = e / MAXSPAN, d = e - i * MAXSPAN;
      int fi = i * S + i + d;
      if (key > T) {
        int p = atomicAdd(&cnt_gt, 1);
        if (p < 1024) idxbuf[p] = fi;
      } else {
        int p = atomicAdd(&cnt_eq, 1);
        if (p < 64) tiebuf[p] = fi;
      }
    }
  }
  __syncthreads();
  if (tid == 0) {
    int ngt = cnt_gt < 1024 ? cnt_gt : 1024;
    int ne = cnt_eq < 64 ? cnt_eq : 64;
    for (int a2 = 1; a2 < ne; a2++) {
      int kv = tiebuf[a2];
      int b2 = a2 - 1;
      while (b2 >= 0 && tiebuf[b2] > kv) { tiebuf[b2 + 1] = tiebuf[b2]; b2--; }
      tiebuf[b2 + 1] = kv;
    }
    int take = remk < ne ? remk : ne;
    for (int q = 0; q < take; q++)
      if (ngt + q < 1024) idxbuf[ngt + q] = tiebuf[q];
  }
  __syncthreads();

  sb[tid] = (tid < MAXK) ? idxbuf[tid] : 0x7FFFFFFF;
  __syncthreads();
  for (int ksz = 2; ksz <= 1024; ksz <<= 1) {
    for (int jj = ksz >> 1; jj > 0; jj >>= 1) {
      int ixj = tid ^ jj;
      if (ixj > tid) {
        int a2 = sb[tid], b2 = sb[ixj];
        bool up = ((tid & ksz) == 0);
        if (up ? (a2 > b2) : (a2 < b2)) { sb[tid] = b2; sb[ixj] = a2; }
      }
      __syncthreads();
    }
  }
  if (tid < MAXK) {
    int fi = sb[tid];
    out[O_START + tid] = (float)(fi >> 12);
    out[O_END + tid]   = (float)(fi & 4095);
    out[O_MASK + tid]  = 1.0f;
  }
}

// ---------------- launch ----------------

extern "C" void kernel_launch(void* const* d_in, const int* in_sizes, int n_in,
                              void* d_out, int out_size, void* d_ws, size_t ws_size,
                              hipStream_t stream) {
  (void)in_sizes; (void)n_in; (void)out_size; (void)ws_size;
  const float* seq    = (const float*)d_in[0];
  const int*   gold   = (const int*)d_in[2];
  const float* W_sm   = (const float*)d_in[3];
  const float* b_sm   = (const float*)d_in[4];
  const float* g_sm   = (const float*)d_in[5];
  const float* be_sm  = (const float*)d_in[6];
  const float* W_em   = (const float*)d_in[7];
  const float* b_em   = (const float*)d_in[8];
  const float* g_em   = (const float*)d_in[9];
  const float* be_em  = (const float*)d_in[10];
  const float* w_st   = (const float*)d_in[11];
  const float* b_st   = (const float*)d_in[12];
  const float* w_en   = (const float*)d_in[13];
  const float* b_en   = (const float*)d_in[14];
  const float* W_s2e  = (const float*)d_in[15];
  const float* b_s2e  = (const float*)d_in[16];
  float* out = (float*)d_out;
  char* ws = (char*)d_ws;

  const size_t SZ_REP = (size_t)S * FF * 4;          // 50331648
  float*  bufS = (float*)(ws);                       // h_start f32 (gelu out, pre-LN)
  float*  bufE = (float*)(ws + SZ_REP);              // h_end -> end_reps f32
  float*  bufT = (float*)(ws + 2 * SZ_REP);          // temp f32
  // R3: seq hi/lo tiled during GEMM1/2; reused as a3 (normalized start) hi/lo tiled
  char* R3 = ws + 3 * SZ_REP;
  unsigned short* seqhi = (unsigned short*)R3;
  unsigned short* seqlo = (unsigned short*)(R3 + (size_t)S * H * 2);
  unsigned short* a3hi  = (unsigned short*)R3;
  unsigned short* a3lo  = (unsigned short*)(R3 + (size_t)S * FF * 2);
  // R4: tiled weight hi/lo (max = W_s2e)
  char* R4 = ws + 4 * SZ_REP;
  unsigned short* wbhi = (unsigned short*)R4;
  unsigned short* wblo = (unsigned short*)(R4 + (size_t)FF * FF * 2);
  // R5: small
  char* R5 = R4 + 2 * (size_t)FF * FF * 2;
  float*  band = (float*)R5;                          // NBAND f32
  char*   mark = R5 + (size_t)NBAND * 4;
  double* jacc = (double*)(R5 + (size_t)NBAND * 4 + NBAND + 32);
  float*  slog = (float*)(R5 + (size_t)NBAND * 4 + NBAND + 128);
  float*  elog = slog + S;
  float*  muS  = elog + S;
  float*  rstdS = muS + S;

  hipMemsetAsync(mark, 0, NBAND, stream);
  hipMemsetAsync(jacc, 0, 8, stream);

  dim3 gg(FF / 128, S / 128);   // (24, 32)

  // seq -> tiled hi/lo (M=S, K=H)
  pack_a_kernel<<<dim3(H / 32, S / 32), 256, 0, stream>>>(seq, seqhi, seqlo, H);
  // W_sm -> tiled B^T hi/lo ; GEMM1 (gelu)
  pack_bt_kernel<<<dim3(H / 32, FF / 32), 256, 0, stream>>>(W_sm, wbhi, wblo, H, FF);
  gemm_mfma_kernel<1><<<gg, 256, 0, stream>>>(seqhi, seqlo, wbhi, wblo, b_sm, bufS, S, FF, H);
  // start-branch stats only (no writeback): mu/rstd/slog
  ln_dot_kernel<0><<<S, 256, 0, stream>>>(bufS, g_sm, be_sm, w_st, b_st, slog, muS, rstdS);
  // W_em -> tiled ; GEMM2 ; end-branch LN with writeback (band needs normalized f32)
  pack_bt_kernel<<<dim3(H / 32, FF / 32), 256, 0, stream>>>(W_em, wbhi, wblo, H, FF);
  gemm_mfma_kernel<1><<<gg, 256, 0, stream>>>(seqhi, seqlo, wbhi, wblo, b_em, bufE, S, FF, H);
  ln_dot_kernel<1><<<S, 256, 0, stream>>>(bufE, g_em, be_em, w_en, b_en, elog, nullptr, nullptr);
  // start_reps tiled hi/lo via fused LN pack (seq tiled dead now) ; W_s2e tiled ; GEMM3
  pack_ln_a_kernel<<<dim3(FF / 32, S / 32), 256, 0, stream>>>(bufS, muS, rstdS, g_sm, be_sm, a3hi, a3lo, FF);
  pack_bt_kernel<<<dim3(FF / 32, FF / 32), 256, 0, stream>>>(W_s2e, wbhi, wblo, FF, FF);
  gemm_mfma_kernel<0><<<gg, 256, 0, stream>>>(a3hi, a3lo, wbhi, wblo, b_s2e, bufT, S, FF, FF);

  band_joint_kernel<<<S / 16, 256, 0, stream>>>(bufT, bufE, slog, elog, band);

  mark_gold_kernel<<<1, 128, 0, stream>>>(gold, mark);
  cost_junk_kernel<<<NBAND / 256, 256, 0, stream>>>(band, mark, jacc);
  topk_kernel<<<1, 1024, 0, stream>>>(band, out);
  finalize_kernel<<<1, 256, 0, stream>>>(band, gold, jacc, out + O_COST);

  hipMemcpyAsync(out + O_SEQ, seq, (size_t)S * H * 4, hipMemcpyDeviceToDevice, stream);
}

// Round 5
// 824.350 us; speedup vs baseline: 2.5626x; 1.0182x over previous
//
#include <hip/hip_runtime.h>
#include <math.h>

#define S 4096
#define H 1024
#define FF 3072
#define G 100
#define MAXSPAN 30
#define MAXK 819
#define NBAND (S * MAXSPAN)   // 122880 slots, 122445 valid
#define BAND_COUNT 122445.0

// out layout (float32)
#define O_START 0
#define O_END   819
#define O_MASK  1638
#define O_SEQ   2457
#define O_COST  (2457 + S * H)   // 4196761

typedef __bf16 bf16x8 __attribute__((ext_vector_type(8)));
typedef float f32x4 __attribute__((ext_vector_type(4)));
typedef float f32x16 __attribute__((ext_vector_type(16)));

// ---------------- helpers ----------------

__device__ __forceinline__ float block_reduce_256(float x, volatile float* red) {
  #pragma unroll
  for (int off = 32; off > 0; off >>= 1) x += __shfl_down(x, off, 64);
  int wid = threadIdx.x >> 6;
  int lane = threadIdx.x & 63;
  __syncthreads();
  if (lane == 0) red[wid] = x;
  __syncthreads();
  return red[0] + red[1] + red[2] + red[3];
}

__device__ __forceinline__ unsigned f2key(float f) {
  unsigned b = __float_as_uint(f);
  return (b & 0x80000000u) ? ~b : (b | 0x80000000u);
}

__device__ __forceinline__ unsigned short bf16_rne(float x) {
  unsigned u = __float_as_uint(x);
  unsigned r = ((u >> 16) & 1u) + 0x7FFFu;
  return (unsigned short)((u + r) >> 16);
}

__device__ __forceinline__ void split2(float x, unsigned short& h, unsigned short& l) {
  h = bf16_rne(x);
  float hf = __uint_as_float(((unsigned)h) << 16);
  l = bf16_rne(x - hf);
}

__device__ __forceinline__ void gld16(const void* g, void* l) {
  __builtin_amdgcn_global_load_lds(
      (const __attribute__((address_space(1))) unsigned int*)g,
      (__attribute__((address_space(3))) unsigned int*)l, 16, 0, 0);
}

// ---------------- pack kernels: f32 -> hi/lo bf16, tiled [panel][kq][r][8] ----------------
// tiled element offset = panel*(128*K) + kq*1024 + r*8 + s   (panel = row/128, kq = k/8)

__global__ __launch_bounds__(256) void pack_a_kernel(const float* __restrict__ A,
                                                     unsigned short* __restrict__ hi,
                                                     unsigned short* __restrict__ lo,
                                                     int K) {
  __shared__ float tile[32][33];
  const int t = threadIdx.x;
  const int tx = t & 31, ty8 = t >> 5;
  const int k0 = blockIdx.x * 32, r0 = blockIdx.y * 32;
  #pragma unroll
  for (int r = ty8; r < 32; r += 8)
    tile[r][tx] = A[(size_t)(r0 + r) * K + k0 + tx];
  __syncthreads();
  if (t < 128) {
    const int kql = t >> 5;
    const int rl = t & 31;
    unsigned short h8[8], l8[8];
    #pragma unroll
    for (int s = 0; s < 8; s++) split2(tile[rl][kql * 8 + s], h8[s], l8[s]);
    const size_t panel = (size_t)(r0 >> 7);
    const int rloc = (r0 & 127) + rl;
    const size_t off = panel * (size_t)(128 * K) + (size_t)(k0 / 8 + kql) * 1024 + (size_t)rloc * 8;
    *(uint4*)(hi + off) = *(const uint4*)h8;
    *(uint4*)(lo + off) = *(const uint4*)l8;
  }
}

// A-side with fused LayerNorm: val = (A - mu[row]) * rstd[row] * g[k] + beta[k]
__global__ __launch_bounds__(256) void pack_ln_a_kernel(const float* __restrict__ A,
                                                        const float* __restrict__ mu,
                                                        const float* __restrict__ rstd,
                                                        const float* __restrict__ g,
                                                        const float* __restrict__ beta,
                                                        unsigned short* __restrict__ hi,
                                                        unsigned short* __restrict__ lo,
                                                        int K) {
  __shared__ float tile[32][33];
  const int t = threadIdx.x;
  const int tx = t & 31, ty8 = t >> 5;
  const int k0 = blockIdx.x * 32, r0 = blockIdx.y * 32;
  #pragma unroll
  for (int r = ty8; r < 32; r += 8)
    tile[r][tx] = A[(size_t)(r0 + r) * K + k0 + tx];
  __syncthreads();
  if (t < 128) {
    const int kql = t >> 5;
    const int rl = t & 31;
    const int row = r0 + rl;
    const float m = mu[row], rs = rstd[row];
    float4 g0 = *(const float4*)(g + k0 + kql * 8);
    float4 g1 = *(const float4*)(g + k0 + kql * 8 + 4);
    float4 b0 = *(const float4*)(beta + k0 + kql * 8);
    float4 b1 = *(const float4*)(beta + k0 + kql * 8 + 4);
    float gv[8] = {g0.x, g0.y, g0.z, g0.w, g1.x, g1.y, g1.z, g1.w};
    float bv[8] = {b0.x, b0.y, b0.z, b0.w, b1.x, b1.y, b1.z, b1.w};
    unsigned short h8[8], l8[8];
    #pragma unroll
    for (int s = 0; s < 8; s++) {
      float v = (tile[rl][kql * 8 + s] - m) * rs * gv[s] + bv[s];
      split2(v, h8[s], l8[s]);
    }
    const size_t panel = (size_t)(r0 >> 7);
    const int rloc = (r0 & 127) + rl;
    const size_t off = panel * (size_t)(128 * K) + (size_t)(k0 / 8 + kql) * 1024 + (size_t)rloc * 8;
    *(uint4*)(hi + off) = *(const uint4*)h8;
    *(uint4*)(lo + off) = *(const uint4*)l8;
  }
}

__global__ __launch_bounds__(256) void pack_bt_kernel(const float* __restrict__ W,
                                                      unsigned short* __restrict__ hi,
                                                      unsigned short* __restrict__ lo,
                                                      int K, int N) {
  __shared__ float tile[32][33];   // tile[k_local][n_local]
  const int t = threadIdx.x;
  const int tx = t & 31, ty8 = t >> 5;
  const int k0 = blockIdx.x * 32, n0 = blockIdx.y * 32;
  #pragma unroll
  for (int r = ty8; r < 32; r += 8)
    tile[r][tx] = W[(size_t)(k0 + r) * N + n0 + tx];
  __syncthreads();
  if (t < 128) {
    const int kql = t >> 5;
    const int nl = t & 31;
    unsigned short h8[8], l8[8];
    #pragma unroll
    for (int s = 0; s < 8; s++) split2(tile[kql * 8 + s][nl], h8[s], l8[s]);
    const size_t panel = (size_t)(n0 >> 7);
    const int nloc = (n0 & 127) + nl;
    const size_t off = panel * (size_t)(128 * K) + (size_t)(k0 / 8 + kql) * 1024 + (size_t)nloc * 8;
    *(uint4*)(hi + off) = *(const uint4*)h8;
    *(uint4*)(lo + off) = *(const uint4*)l8;
  }
}

// ---------------- MFMA GEMM core (32x32x16, 3-product split) ----------------

template <int EPI>
__device__ __forceinline__ void gemm_body(const char* cAh, const char* cAl,
                                          const char* cBh, const char* cBl,
                                          const float* __restrict__ bias,
                                          float* __restrict__ C,
                                          int bm, int bn, int N, int K,
                                          char* smem) {
  const int tid = threadIdx.x;
  const int lane = tid & 63;
  const int wid = __builtin_amdgcn_readfirstlane(tid >> 6);
  const int wm = wid >> 1, wn = wid & 1;
  const int lb = lane * 16;
  const int ldsq = wid * 2048;

  const int khalf = lane >> 5;
  const int r31 = lane & 31;
  const int abase = khalf * 2048 + (wm * 64 + r31) * 16;
  const int bbase = khalf * 2048 + (wn * 64 + r31) * 16;

  f32x16 acc[2][2];
  #pragma unroll
  for (int a = 0; a < 2; a++)
    #pragma unroll
    for (int b = 0; b < 2; b++)
      #pragma unroll
      for (int r = 0; r < 16; r++) acc[a][b][r] = 0.0f;

  for (int k0 = 0; k0 < K; k0 += 32) {
    const size_t qb = (size_t)((k0 >> 3) + wid) * 2048 + lb;
    __syncthreads();
    gld16(cAh + qb,        smem +     0 + ldsq);
    gld16(cAh + qb + 1024, smem +     0 + ldsq + 1024);
    gld16(cAl + qb,        smem +  8192 + ldsq);
    gld16(cAl + qb + 1024, smem +  8192 + ldsq + 1024);
    gld16(cBh + qb,        smem + 16384 + ldsq);
    gld16(cBh + qb + 1024, smem + 16384 + ldsq + 1024);
    gld16(cBl + qb,        smem + 24576 + ldsq);
    gld16(cBl + qb + 1024, smem + 24576 + ldsq + 1024);
    __syncthreads();

    bf16x8 ah[2][2], al[2][2], bh[2][2], bl[2][2];
    #pragma unroll
    for (int ks = 0; ks < 2; ks++) {
      #pragma unroll
      for (int mt = 0; mt < 2; mt++) {
        ah[ks][mt] = *(const bf16x8*)(smem +     0 + ks * 4096 + abase + mt * 512);
        al[ks][mt] = *(const bf16x8*)(smem +  8192 + ks * 4096 + abase + mt * 512);
      }
      #pragma unroll
      for (int nt = 0; nt < 2; nt++) {
        bh[ks][nt] = *(const bf16x8*)(smem + 16384 + ks * 4096 + bbase + nt * 512);
        bl[ks][nt] = *(const bf16x8*)(smem + 24576 + ks * 4096 + bbase + nt * 512);
      }
    }
    #pragma unroll
    for (int ks = 0; ks < 2; ks++)
      #pragma unroll
      for (int mt = 0; mt < 2; mt++)
        #pragma unroll
        for (int nt = 0; nt < 2; nt++) {
          acc[mt][nt] = __builtin_amdgcn_mfma_f32_32x32x16_bf16(ah[ks][mt], bh[ks][nt], acc[mt][nt], 0, 0, 0);
          acc[mt][nt] = __builtin_amdgcn_mfma_f32_32x32x16_bf16(al[ks][mt], bh[ks][nt], acc[mt][nt], 0, 0, 0);
          acc[mt][nt] = __builtin_amdgcn_mfma_f32_32x32x16_bf16(ah[ks][mt], bl[ks][nt], acc[mt][nt], 0, 0, 0);
        }
  }

  #pragma unroll
  for (int mt = 0; mt < 2; mt++) {
    #pragma unroll
    for (int nt = 0; nt < 2; nt++) {
      const int colg = bn + wn * 64 + nt * 32 + r31;
      const float bb = bias[colg];
      #pragma unroll
      for (int reg = 0; reg < 16; reg++) {
        const int rowl = (reg & 3) + 8 * (reg >> 2) + 4 * khalf;
        const int rowg = bm + wm * 64 + mt * 32 + rowl;
        float v = acc[mt][nt][reg] + bb;
        if (EPI == 1) v = 0.5f * v * (1.0f + erff(v * 0.70710678118654752f));
        C[(size_t)rowg * N + colg] = v;
      }
    }
  }
}

// GEMM3: single output
__global__ __launch_bounds__(256) void gemm_mfma_kernel(const unsigned short* __restrict__ Ahi,
                                                        const unsigned short* __restrict__ Alo,
                                                        const unsigned short* __restrict__ Bhi,
                                                        const unsigned short* __restrict__ Blo,
                                                        const float* __restrict__ bias,
                                                        float* __restrict__ C,
                                                        int N, int K) {
  __shared__ __align__(16) char smem[32768];
  const size_t panAb = (size_t)blockIdx.y * (size_t)(128 * K) * 2;
  const size_t panBb = (size_t)blockIdx.x * (size_t)(128 * K) * 2;
  gemm_body<0>((const char*)Ahi + panAb, (const char*)Alo + panAb,
               (const char*)Bhi + panBb, (const char*)Blo + panBb,
               bias, C, blockIdx.y * 128, blockIdx.x * 128, N, K, smem);
}

// GEMM1+2 fused: blockIdx.z picks branch (same A)
__global__ __launch_bounds__(256) void gemm_mfma_dual_kernel(const unsigned short* __restrict__ Ahi,
                                                             const unsigned short* __restrict__ Alo,
                                                             const unsigned short* __restrict__ B1hi,
                                                             const unsigned short* __restrict__ B1lo,
                                                             const unsigned short* __restrict__ B2hi,
                                                             const unsigned short* __restrict__ B2lo,
                                                             const float* __restrict__ bias1,
                                                             const float* __restrict__ bias2,
                                                             float* __restrict__ C1,
                                                             float* __restrict__ C2,
                                                             int N, int K) {
  __shared__ __align__(16) char smem[32768];
  const int zb = blockIdx.z;
  const unsigned short* Bhi = zb ? B2hi : B1hi;
  const unsigned short* Blo = zb ? B2lo : B1lo;
  const float* bias = zb ? bias2 : bias1;
  float* C = zb ? C2 : C1;
  const size_t panAb = (size_t)blockIdx.y * (size_t)(128 * K) * 2;
  const size_t panBb = (size_t)blockIdx.x * (size_t)(128 * K) * 2;
  gemm_body<1>((const char*)Ahi + panAb, (const char*)Alo + panAb,
               (const char*)Bhi + panBb, (const char*)Blo + panBb,
               bias, C, blockIdx.y * 128, blockIdx.x * 128, N, K, smem);
}

// ---------------- LN stats + logit (no writeback), both branches ----------------
// grid (S, 2): y=0 start branch, y=1 end branch

__global__ __launch_bounds__(256) void ln_stats_kernel(const float* __restrict__ HbS,
                                                       const float* __restrict__ HbE,
                                                       const float* __restrict__ gS,
                                                       const float* __restrict__ betaS,
                                                       const float* __restrict__ wS,
                                                       const float* __restrict__ bS,
                                                       const float* __restrict__ gE,
                                                       const float* __restrict__ betaE,
                                                       const float* __restrict__ wE,
                                                       const float* __restrict__ bE,
                                                       float* __restrict__ slog,
                                                       float* __restrict__ elog,
                                                       float* __restrict__ muS,
                                                       float* __restrict__ rstdS,
                                                       float* __restrict__ muE,
                                                       float* __restrict__ rstdE) {
  __shared__ float red[4];
  const int row = blockIdx.x, tid = threadIdx.x;
  const int br = blockIdx.y;
  const float* Hb = br ? HbE : HbS;
  const float* g = br ? gE : gS;
  const float* beta = br ? betaE : betaS;
  const float* w = br ? wE : wS;
  const float* bsc = br ? bE : bS;
  const float* h = Hb + (size_t)row * FF;

  float4 v[3];
  float s = 0.0f;
  #pragma unroll
  for (int t = 0; t < 3; t++) {
    v[t] = *(const float4*)(h + tid * 4 + t * 1024);
    s += v[t].x + v[t].y + v[t].z + v[t].w;
  }
  float mu = block_reduce_256(s, red) * (1.0f / (float)FF);

  float s2 = 0.0f;
  #pragma unroll
  for (int t = 0; t < 3; t++) {
    float dx = v[t].x - mu, dy = v[t].y - mu, dz = v[t].z - mu, dw = v[t].w - mu;
    s2 += dx * dx + dy * dy + dz * dz + dw * dw;
  }
  float var = block_reduce_256(s2, red) * (1.0f / (float)FF);
  float rstd = rsqrtf(var + 1e-5f);

  float dot = 0.0f;
  #pragma unroll
  for (int t = 0; t < 3; t++) {
    int idx = tid * 4 + t * 1024;
    float4 gv = *(const float4*)(g + idx);
    float4 bv = *(const float4*)(beta + idx);
    float4 wv = *(const float4*)(w + idx);
    float rx = (v[t].x - mu) * rstd * gv.x + bv.x;
    float ry = (v[t].y - mu) * rstd * gv.y + bv.y;
    float rz = (v[t].z - mu) * rstd * gv.z + bv.z;
    float rw = (v[t].w - mu) * rstd * gv.w + bv.w;
    dot += rx * wv.x + ry * wv.y + rz * wv.z + rw * wv.w;
  }
  float dt = block_reduce_256(dot, red);
  if (tid == 0) {
    if (br) { elog[row] = dt + bsc[0]; muE[row] = mu; rstdE[row] = rstd; }
    else    { slog[row] = dt + bsc[0]; muS[row] = mu; rstdS[row] = rstd; }
  }
}

// ---------------- band joint (tiled, LDS E-chunk, inline E-LayerNorm, XCD swizzle) ----------------

__global__ __launch_bounds__(256) void band_joint_kernel(const float* __restrict__ T,
                                                         const float* __restrict__ Eraw,
                                                         const float* __restrict__ muE,
                                                         const float* __restrict__ rstdE,
                                                         const float* __restrict__ gE,
                                                         const float* __restrict__ betaE,
                                                         const float* __restrict__ sl,
                                                         const float* __restrict__ el,
                                                         float* __restrict__ band) {
  __shared__ float Elds[45][260];   // 260 = 256 + 4 pad
  const int t = threadIdx.x;
  // XCD-locality swizzle: consecutive i0 groups co-resident per XCD (perf heuristic only)
  const int bx = blockIdx.x;
  const int sbx = (bx & 7) * 32 + (bx >> 3);
  const int i0 = sbx * 16;
  const int r_l = t >> 4, c = t & 15;

  float accd[MAXSPAN];
  #pragma unroll
  for (int d = 0; d < MAXSPAN; d++) accd[d] = 0.0f;

  for (int k0 = 0; k0 < FF; k0 += 256) {
    const float* trow = T + (size_t)(i0 + r_l) * FF + k0 + c * 16;
    float4 tv0 = *(const float4*)(trow + 0);
    float4 tv1 = *(const float4*)(trow + 4);
    float4 tv2 = *(const float4*)(trow + 8);
    float4 tv3 = *(const float4*)(trow + 12);
    __syncthreads();
    for (int rr = t >> 6; rr < 45; rr += 4) {
      int gr = i0 + rr;
      int cc = (t & 63) * 4;
      float4 rv = {0.f, 0.f, 0.f, 0.f};
      if (gr < S) {
        float4 ev = *(const float4*)(Eraw + (size_t)gr * FF + k0 + cc);
        float m = muE[gr], rs = rstdE[gr];
        float4 gv = *(const float4*)(gE + k0 + cc);
        float4 bv = *(const float4*)(betaE + k0 + cc);
        rv.x = (ev.x - m) * rs * gv.x + bv.x;
        rv.y = (ev.y - m) * rs * gv.y + bv.y;
        rv.z = (ev.z - m) * rs * gv.z + bv.z;
        rv.w = (ev.w - m) * rs * gv.w + bv.w;
      }
      *(float4*)&Elds[rr][cc] = rv;
    }
    __syncthreads();
    #pragma unroll
    for (int d = 0; d < MAXSPAN; d++) {
      const float* er = &Elds[r_l + d][c * 16];
      float4 e0 = *(const float4*)(er + 0);
      float4 e1 = *(const float4*)(er + 4);
      float4 e2 = *(const float4*)(er + 8);
      float4 e3 = *(const float4*)(er + 12);
      accd[d] += tv0.x * e0.x + tv0.y * e0.y + tv0.z * e0.z + tv0.w * e0.w
               + tv1.x * e1.x + tv1.y * e1.y + tv1.z * e1.z + tv1.w * e1.w
               + tv2.x * e2.x + tv2.y * e2.y + tv2.z * e2.z + tv2.w * e2.w
               + tv3.x * e3.x + tv3.y * e3.y + tv3.z * e3.z + tv3.w * e3.w;
    }
  }

  const int i = i0 + r_l;
  const float my_sl = sl[i];
  #pragma unroll
  for (int d = 0; d < MAXSPAN; d++) {
    float v = accd[d];
    v += __shfl_down(v, 8, 16);
    v += __shfl_down(v, 4, 16);
    v += __shfl_down(v, 2, 16);
    v += __shfl_down(v, 1, 16);
    if (c == 0) {
      int j = i + d;
      if (j < S) {
        float vv = v + my_sl + el[j];
        vv = fminf(fmaxf(vv, -10000.0f), 10000.0f);
        band[i * MAXSPAN + d] = vv;
      } else {
        band[i * MAXSPAN + d] = -1e30f;
      }
    }
  }
}

// ---------------- gold marking + costs ----------------

__global__ void mark_gold_kernel(const int* __restrict__ gold, char* __restrict__ mark) {
  int t = threadIdx.x;
  if (t < G) {
    int gs = gold[2 * t], ge = gold[2 * t + 1];
    mark[gs * MAXSPAN + (ge - gs)] = 1;
  }
}

__global__ __launch_bounds__(256) void cost_junk_kernel(const float* __restrict__ band,
                                                        const char* __restrict__ mark,
                                                        double* __restrict__ jacc) {
  __shared__ float red[4];
  int e = blockIdx.x * 256 + threadIdx.x;
  int i = e / MAXSPAN, d = e - i * MAXSPAN;
  float term = 0.0f;
  if (i + d < S && !mark[e]) {
    float x = band[e];
    float p = 1.0f / (1.0f + expf(-x));
    term = fmaxf(logf(1.0f - p), -100.0f);
  }
  float ssum = block_reduce_256(term, red);
  if (threadIdx.x == 0) atomicAdd(jacc, (double)ssum);
}

__global__ __launch_bounds__(256) void finalize_kernel(const float* __restrict__ band,
                                                       const int* __restrict__ gold,
                                                       const double* __restrict__ jacc,
                                                       float* __restrict__ outc) {
  __shared__ float red[4];
  int t = threadIdx.x;
  float term = 0.0f;
  if (t < G) {
    int gs = gold[2 * t], ge = gold[2 * t + 1];
    float x = band[gs * MAXSPAN + (ge - gs)];
    float p = 1.0f / (1.0f + expf(-x));
    term = fmaxf(logf(p), -100.0f);
  }
  float sg = block_reduce_256(term, red);
  if (t == 0) {
    double cost = -((double)sg / (double)G) - ((*jacc) / BAND_COUNT);
    *outc = (float)cost;
  }
}

// ---------------- top-k (single block, 2-pass 16-bit radix + tie resolve + bitonic) ----------------

__global__ __launch_bounds__(1024) void topk_kernel(const float* __restrict__ band,
                                                    float* __restrict__ out) {
  __shared__ int hist[256];
  __shared__ unsigned sh_prefix;
  __shared__ int sh_remk;
  __shared__ int idxbuf[1024];
  __shared__ unsigned tkey[256];
  __shared__ int tidx[256];
  __shared__ int cnt_gt, cnt_eq;
  __shared__ int sb[1024];
  const int tid = threadIdx.x;

  // pass 0: top 8 bits
  if (tid < 256) hist[tid] = 0;
  __syncthreads();
  for (int e = tid; e < NBAND; e += 1024)
    atomicAdd(&hist[f2key(band[e]) >> 24], 1);
  __syncthreads();
  if (tid == 0) {
    int cum = 0, b = 255;
    for (; b > 0; b--) {
      if (cum + hist[b] >= MAXK) break;
      cum += hist[b];
    }
    sh_prefix = (unsigned)b;
    sh_remk = MAXK - cum;
  }
  __syncthreads();
  const unsigned p8 = sh_prefix;
  int remk = sh_remk;
  __syncthreads();

  // pass 1: bits 23..16 within prefix
  if (tid < 256) hist[tid] = 0;
  __syncthreads();
  for (int e = tid; e < NBAND; e += 1024) {
    unsigned key = f2key(band[e]);
    if ((key >> 24) == p8) atomicAdd(&hist[(key >> 16) & 255], 1);
  }
  __syncthreads();
  if (tid == 0) {
    int cum = 0, b = 255;
    for (; b > 0; b--) {
      if (cum + hist[b] >= remk) break;
      cum += hist[b];
    }
    sh_prefix = (p8 << 8) | (unsigned)b;
    sh_remk = remk - cum;
  }
  __syncthreads();
  const unsigned T16 = sh_prefix;
  remk = sh_remk;

  if (tid == 0) { cnt_gt = 0; cnt_eq = 0; }
  __syncthreads();
  for (int e = tid; e < NBAND; e += 1024) {
    unsigned key = f2key(band[e]);
    unsigned k16 = key >> 16;
    if (k16 >= T16) {
      int i = e / MAXSPAN, d = e - i * MAXSPAN;
      int fi = i * S + i + d;
      if (k16 > T16) {
        int p = atomicAdd(&cnt_gt, 1);
        if (p < 1024) idxbuf[p] = fi;
      } else {
        int p = atomicAdd(&cnt_eq, 1);
        if (p < 256) { tkey[p] = key; tidx[p] = fi; }
      }
    }
  }
  __syncthreads();
  if (tid == 0) {
    int ngt = cnt_gt < 1024 ? cnt_gt : 1024;
    int ne = cnt_eq < 256 ? cnt_eq : 256;
    // insertion sort ties: key desc, then idx asc
    for (int a2 = 1; a2 < ne; a2++) {
      unsigned kv = tkey[a2]; int iv = tidx[a2];
      int b2 = a2 - 1;
      while (b2 >= 0 && (tkey[b2] < kv || (tkey[b2] == kv && tidx[b2] > iv))) {
        tkey[b2 + 1] = tkey[b2]; tidx[b2 + 1] = tidx[b2]; b2--;
      }
      tkey[b2 + 1] = kv; tidx[b2 + 1] = iv;
    }
    int take = remk < ne ? remk : ne;
    for (int q = 0; q < take; q++)
      if (ngt + q < 1024) idxbuf[ngt + q] = tidx[q];
  }
  __syncthreads();

  sb[tid] = (tid < MAXK) ? idxbuf[tid] : 0x7FFFFFFF;
  __syncthreads();
  for (int ksz = 2; ksz <= 1024; ksz <<= 1) {
    for (int jj = ksz >> 1; jj > 0; jj >>= 1) {
      int ixj = tid ^ jj;
      if (ixj > tid) {
        int a2 = sb[tid], b2 = sb[ixj];
        bool up = ((tid & ksz) == 0);
        if (up ? (a2 > b2) : (a2 < b2)) { sb[tid] = b2; sb[ixj] = a2; }
      }
      __syncthreads();
    }
  }
  if (tid < MAXK) {
    int fi = sb[tid];
    out[O_START + tid] = (float)(fi >> 12);
    out[O_END + tid]   = (float)(fi & 4095);
    out[O_MASK + tid]  = 1.0f;
  }
}

// ---------------- launch ----------------

extern "C" void kernel_launch(void* const* d_in, const int* in_sizes, int n_in,
                              void* d_out, int out_size, void* d_ws, size_t ws_size,
                              hipStream_t stream) {
  (void)in_sizes; (void)n_in; (void)out_size; (void)ws_size;
  const float* seq    = (const float*)d_in[0];
  const int*   gold   = (const int*)d_in[2];
  const float* W_sm   = (const float*)d_in[3];
  const float* b_sm   = (const float*)d_in[4];
  const float* g_sm   = (const float*)d_in[5];
  const float* be_sm  = (const float*)d_in[6];
  const float* W_em   = (const float*)d_in[7];
  const float* b_em   = (const float*)d_in[8];
  const float* g_em   = (const float*)d_in[9];
  const float* be_em  = (const float*)d_in[10];
  const float* w_st   = (const float*)d_in[11];
  const float* b_st   = (const float*)d_in[12];
  const float* w_en   = (const float*)d_in[13];
  const float* b_en   = (const float*)d_in[14];
  const float* W_s2e  = (const float*)d_in[15];
  const float* b_s2e  = (const float*)d_in[16];
  float* out = (float*)d_out;
  char* ws = (char*)d_ws;

  const size_t SZ_REP = (size_t)S * FF * 4;          // 50331648
  float*  bufS = (float*)(ws);                       // h_start f32 (gelu out, pre-LN)
  float*  bufE = (float*)(ws + SZ_REP);              // h_end f32 (gelu out, pre-LN)
  float*  bufT = (float*)(ws + 2 * SZ_REP);          // temp f32
  // R3: seq hi/lo tiled during GEMM1/2; reused as a3 (normalized start) hi/lo tiled
  char* R3 = ws + 3 * SZ_REP;
  unsigned short* seqhi = (unsigned short*)R3;
  unsigned short* seqlo = (unsigned short*)(R3 + (size_t)S * H * 2);
  unsigned short* a3hi  = (unsigned short*)R3;
  unsigned short* a3lo  = (unsigned short*)(R3 + (size_t)S * FF * 2);
  // R4: tiled weights. GEMM1/2 phase: wb1hi/lo + wb2hi/lo (4 x 6.29MB).
  //     GEMM3 phase (after dual GEMM): wbhi/lo (2 x 18.87MB).
  char* R4 = ws + 4 * SZ_REP;
  const size_t SZ_W12 = (size_t)H * FF * 2;          // 6291456
  unsigned short* wb1hi = (unsigned short*)R4;
  unsigned short* wb1lo = (unsigned short*)(R4 + SZ_W12);
  unsigned short* wb2hi = (unsigned short*)(R4 + 2 * SZ_W12);
  unsigned short* wb2lo = (unsigned short*)(R4 + 3 * SZ_W12);
  unsigned short* wbhi = (unsigned short*)R4;
  unsigned short* wblo = (unsigned short*)(R4 + (size_t)FF * FF * 2);
  // R5: small
  char* R5 = R4 + 2 * (size_t)FF * FF * 2;
  float*  band = (float*)R5;                          // NBAND f32
  char*   mark = R5 + (size_t)NBAND * 4;
  double* jacc = (double*)(R5 + (size_t)NBAND * 4 + NBAND + 32);
  float*  slog = (float*)(R5 + (size_t)NBAND * 4 + NBAND + 128);
  float*  elog  = slog + S;
  float*  muS   = elog + S;
  float*  rstdS = muS + S;
  float*  muE   = rstdS + S;
  float*  rstdE = muE + S;

  hipMemsetAsync(mark, 0, NBAND, stream);
  hipMemsetAsync(jacc, 0, 8, stream);

  dim3 gg(FF / 128, S / 128);        // (24, 32)
  dim3 gg2(FF / 128, S / 128, 2);    // fused GEMM1+2

  // seq -> tiled hi/lo (M=S, K=H)
  pack_a_kernel<<<dim3(H / 32, S / 32), 256, 0, stream>>>(seq, seqhi, seqlo, H);
  // both H x FF weights -> tiled B^T hi/lo
  pack_bt_kernel<<<dim3(H / 32, FF / 32), 256, 0, stream>>>(W_sm, wb1hi, wb1lo, H, FF);
  pack_bt_kernel<<<dim3(H / 32, FF / 32), 256, 0, stream>>>(W_em, wb2hi, wb2lo, H, FF);
  // fused GEMM1+2 (gelu epilogue)
  gemm_mfma_dual_kernel<<<gg2, 256, 0, stream>>>(seqhi, seqlo, wb1hi, wb1lo, wb2hi, wb2lo,
                                                 b_sm, b_em, bufS, bufE, FF, H);
  // LN stats + logits for both branches, no writeback
  ln_stats_kernel<<<dim3(S, 2), 256, 0, stream>>>(bufS, bufE, g_sm, be_sm, w_st, b_st,
                                                  g_em, be_em, w_en, b_en,
                                                  slog, elog, muS, rstdS, muE, rstdE);
  // start_reps tiled hi/lo via fused LN pack (seq tiled dead now) ; W_s2e tiled ; GEMM3
  pack_ln_a_kernel<<<dim3(FF / 32, S / 32), 256, 0, stream>>>(bufS, muS, rstdS, g_sm, be_sm, a3hi, a3lo, FF);
  pack_bt_kernel<<<dim3(FF / 32, FF / 32), 256, 0, stream>>>(W_s2e, wbhi, wblo, FF, FF);
  gemm_mfma_kernel<<<gg, 256, 0, stream>>>(a3hi, a3lo, wbhi, wblo, b_s2e, bufT, FF, FF);

  // band joint with inline E-LayerNorm
  band_joint_kernel<<<S / 16, 256, 0, stream>>>(bufT, bufE, muE, rstdE, g_em, be_em,
                                                slog, elog, band);

  mark_gold_kernel<<<1, 128, 0, stream>>>(gold, mark);
  cost_junk_kernel<<<NBAND / 256, 256, 0, stream>>>(band, mark, jacc);
  topk_kernel<<<1, 1024, 0, stream>>>(band, out);
  finalize_kernel<<<1, 256, 0, stream>>>(band, gold, jacc, out + O_COST);

  hipMemcpyAsync(out + O_SEQ, seq, (size_t)S * H * 4, hipMemcpyDeviceToDevice, stream);
}